// Round 1
// baseline (2248.868 us; speedup 1.0000x reference)
//
#include <hip/hip_runtime.h>
#include <math.h>

#define EMBED 1024
#define HEADS 16
#define HDIM  64
#define HIDDEN 4096
#define BATCH 2
#define SEQ   2048
#define TOK   (BATCH * SEQ)   // 4096 tokens

// ---------------------------------------------------------------------------
// GEMM: C[T,N] = act(A[T,K] @ W[K,N] + bias), row-major.
// 128x128 tile, BK=32, 256 threads, 8x8 accumulator per thread (fp32 VALU —
// no fp32 MFMA on CDNA4). As stored transposed [kk][m]; Bs XOR-swizzled on n
// by ((kk&7)<<2) so both staging writes and compute reads are <=2-way banked.
template<int RELU>
__global__ __launch_bounds__(256, 2)
void gemm_bias(const float* __restrict__ A, const float* __restrict__ W,
               const float* __restrict__ bias, float* __restrict__ C,
               int T, int K, int N) {
  __shared__ float As[32][128];   // As[kk][m]
  __shared__ float Bs[32][128];   // Bs[kk][n ^ ((kk&7)<<2)]
  const int tid = threadIdx.x;
  const int m0 = blockIdx.y * 128;
  const int n0 = blockIdx.x * 128;
  const int tx = tid & 15;        // output col group (8 cols)
  const int ty = tid >> 4;        // output row group (8 rows)

  float acc[8][8];
#pragma unroll
  for (int i = 0; i < 8; ++i)
#pragma unroll
    for (int j = 0; j < 8; ++j) acc[i][j] = 0.f;

  // staging assignment: A: 2 threads/row, 16 k each; B: 8 threads/row, 16 n each
  const int ar  = tid >> 1;
  const int ak  = (tid & 1) * 16;
  const int bkr = tid >> 3;
  const int bn  = (tid & 7) * 16;

  const float* Ap = A + (size_t)(m0 + ar) * K + ak;
  const float* Wp = W + (size_t)bkr * N + n0 + bn;

  for (int k0 = 0; k0 < K; k0 += 32) {
#pragma unroll
    for (int c = 0; c < 4; ++c) {           // A: 4x float4, transposed store
      float4 a4 = *reinterpret_cast<const float4*>(Ap + k0 + c * 4);
      As[ak + c * 4 + 0][ar] = a4.x;
      As[ak + c * 4 + 1][ar] = a4.y;
      As[ak + c * 4 + 2][ar] = a4.z;
      As[ak + c * 4 + 3][ar] = a4.w;
    }
#pragma unroll
    for (int c = 0; c < 4; ++c) {           // B: 4x float4, swizzled store
      float4 b4 = *reinterpret_cast<const float4*>(Wp + (size_t)k0 * N + c * 4);
      const int nsw = (bn + c * 4) ^ ((bkr & 7) << 2);
      *reinterpret_cast<float4*>(&Bs[bkr][nsw]) = b4;
    }
    __syncthreads();
#pragma unroll
    for (int kk = 0; kk < 32; ++kk) {
      float a[8], b[8];
      *(float4*)&a[0] = *(float4*)&As[kk][ty * 8];
      *(float4*)&a[4] = *(float4*)&As[kk][ty * 8 + 4];
      const int sb = (kk & 7) << 2;
      *(float4*)&b[0] = *(float4*)&Bs[kk][(tx * 8) ^ sb];
      *(float4*)&b[4] = *(float4*)&Bs[kk][(tx * 8 + 4) ^ sb];
#pragma unroll
      for (int i = 0; i < 8; ++i)
#pragma unroll
        for (int j = 0; j < 8; ++j)
          acc[i][j] = fmaf(a[i], b[j], acc[i][j]);
    }
    __syncthreads();
  }

  float bj[8];
  *(float4*)&bj[0] = *(const float4*)(bias + n0 + tx * 8);
  *(float4*)&bj[4] = *(const float4*)(bias + n0 + tx * 8 + 4);
#pragma unroll
  for (int i = 0; i < 8; ++i) {
    float outv[8];
#pragma unroll
    for (int j = 0; j < 8; ++j) {
      float vv = acc[i][j] + bj[j];
      if (RELU) vv = fmaxf(vv, 0.f);
      outv[j] = vv;
    }
    float* Cp = C + (size_t)(m0 + ty * 8 + i) * N + n0 + tx * 8;
    *(float4*)(Cp)     = *(float4*)&outv[0];
    *(float4*)(Cp + 4) = *(float4*)&outv[4];
  }
}

// ---------------------------------------------------------------------------
// Flash attention, fp32. q/k/v layout: [T][EMBED] with head offset h*64
// (i.e. the projection output untouched). One block = 64 q-rows of one (b,h).
// Online softmax; 64x64 K/V tiles. Thread (ty,tx): ty=tid>>4 owns rows
// r0=ty*4, tx owns keys kc0=tx*4 (score phase) / dims n0=tx*4 (PV phase).
// kp buffer is reused: K^T during scores, then P^T for PV (saves 16 KB).
__global__ __launch_bounds__(256, 2)
void attention(const float* __restrict__ q, const float* __restrict__ k,
               const float* __restrict__ v, float* __restrict__ ctx) {
  __shared__ float qT[64][64];   // qT[d][r], pre-scaled by 1/sqrt(64)
  __shared__ float kp[64][64];   // kT[d][kc^ksw(d)]  then  pT[kc][r^((kc&15)<<2)]
  __shared__ float vs[64][64];   // vs[kc][d^((kc&7)<<2)]
  const int tid = threadIdx.x;
  const int bh = blockIdx.y;
  const int b = bh >> 4, h = bh & 15;
  const int s0 = blockIdx.x * 64;
  const int tx = tid & 15, ty = tid >> 4;
  const int r0 = ty * 4, n0 = tx * 4;

  { // stage Q tile (transposed, scaled)
    const int rr = tid >> 2, d0 = (tid & 3) * 16;
    const float* qp = q + (size_t)(b * SEQ + s0 + rr) * EMBED + h * HDIM + d0;
#pragma unroll
    for (int c = 0; c < 4; ++c) {
      float4 f = *(const float4*)(qp + c * 4);
      qT[d0 + c * 4 + 0][rr] = f.x * 0.125f;
      qT[d0 + c * 4 + 1][rr] = f.y * 0.125f;
      qT[d0 + c * 4 + 2][rr] = f.z * 0.125f;
      qT[d0 + c * 4 + 3][rr] = f.w * 0.125f;
    }
  }

  float m[4], l[4], o[4][4];
#pragma unroll
  for (int i = 0; i < 4; ++i) {
    m[i] = -1e30f; l[i] = 0.f;
#pragma unroll
    for (int j = 0; j < 4; ++j) o[i][j] = 0.f;
  }
  __syncthreads();

  // staging constants: thread covers row kc_s, dims d0_s..d0_s+15
  const int kc_s = tid >> 2, d0_s = (tid & 3) * 16;
  // kT swizzle: element (d,kc) -> kp[d][kc ^ ksw(d)], ksw from d bits 4..5
  const int ksw = (((tid & 3) & 1) << 4) | ((((tid & 3) >> 1) & 1) << 3);
  const int vsw = (kc_s & 7) << 2;
  const float* kbase = k + (size_t)(b * SEQ + kc_s) * EMBED + h * HDIM + d0_s;
  const float* vbase = v + (size_t)(b * SEQ + kc_s) * EMBED + h * HDIM + d0_s;

  for (int kt = 0; kt < SEQ / 64; ++kt) {
    { // stage K^T and V for this tile
      const float* kpp = kbase + (size_t)kt * 64 * EMBED;
      const float* vpp = vbase + (size_t)kt * 64 * EMBED;
#pragma unroll
      for (int c = 0; c < 4; ++c) {
        float4 f = *(const float4*)(kpp + c * 4);
        const int d = d0_s + c * 4;
        kp[d + 0][kc_s ^ ksw] = f.x;
        kp[d + 1][kc_s ^ ksw] = f.y;
        kp[d + 2][kc_s ^ ksw] = f.z;
        kp[d + 3][kc_s ^ ksw] = f.w;
        float4 g = *(const float4*)(vpp + c * 4);
        *(float4*)&vs[kc_s][d ^ vsw] = g;
      }
    }
    __syncthreads();

    // scores: s[i][j] = (q_{r0+i} . k_{kc0+j}) / 8
    float s[4][4];
#pragma unroll
    for (int i = 0; i < 4; ++i)
#pragma unroll
      for (int j = 0; j < 4; ++j) s[i][j] = 0.f;
#pragma unroll 8
    for (int d = 0; d < 64; ++d) {
      float qa[4], kb[4];
      *(float4*)qa = *(float4*)&qT[d][r0];
      const int ks = (((d >> 4) & 1) << 4) | (((d >> 5) & 1) << 3);
      *(float4*)kb = *(float4*)&kp[d][(tx * 4) ^ ks];
#pragma unroll
      for (int i = 0; i < 4; ++i)
#pragma unroll
        for (int j = 0; j < 4; ++j)
          s[i][j] = fmaf(qa[i], kb[j], s[i][j]);
    }

    // online softmax (row reduce across the 16 tx lanes; same-ty lanes are
    // 16 consecutive lanes in-wave, so shfl_xor 1/2/4/8 stays in-group)
    float mn[4], al[4];
#pragma unroll
    for (int i = 0; i < 4; ++i) {
      float mt = fmaxf(fmaxf(s[i][0], s[i][1]), fmaxf(s[i][2], s[i][3]));
      for (int off = 1; off < 16; off <<= 1) mt = fmaxf(mt, __shfl_xor(mt, off));
      mn[i] = fmaxf(m[i], mt);
      al[i] = __expf(m[i] - mn[i]);
    }
#pragma unroll
    for (int i = 0; i < 4; ++i) {
#pragma unroll
      for (int j = 0; j < 4; ++j) s[i][j] = __expf(s[i][j] - mn[i]);
      float rs = s[i][0] + s[i][1] + s[i][2] + s[i][3];
      for (int off = 1; off < 16; off <<= 1) rs += __shfl_xor(rs, off);
      l[i] = l[i] * al[i] + rs;
      m[i] = mn[i];
#pragma unroll
      for (int j = 0; j < 4; ++j) o[i][j] *= al[i];
    }
    __syncthreads();   // all lanes done reading kp as K^T

    // write P^T into kp (swizzled so the 64-lane write spreads all 32 banks)
#pragma unroll
    for (int j = 0; j < 4; ++j) {
      const int kc = n0 + j;  // key index (tx*4+j)
      const int pr = r0 ^ ((kc & 15) << 2);
      float4 pv = make_float4(s[0][j], s[1][j], s[2][j], s[3][j]);
      *(float4*)&kp[kc][pr] = pv;
    }
    __syncthreads();   // P^T visible

    // PV: o[i][j] += P[r0+i][kc] * v[kc][n0+j]
#pragma unroll 8
    for (int kc = 0; kc < 64; ++kc) {
      float pa[4], vb[4];
      *(float4*)pa = *(float4*)&kp[kc][r0 ^ ((kc & 15) << 2)];
      *(float4*)vb = *(float4*)&vs[kc][n0 ^ ((kc & 7) << 2)];
#pragma unroll
      for (int i = 0; i < 4; ++i)
#pragma unroll
        for (int j = 0; j < 4; ++j)
          o[i][j] = fmaf(pa[i], vb[j], o[i][j]);
    }
    __syncthreads();   // done reading kp/vs before next tile's staging
  }

#pragma unroll
  for (int i = 0; i < 4; ++i) {
    const float inv = 1.f / l[i];
    float4 ov = make_float4(o[i][0] * inv, o[i][1] * inv,
                            o[i][2] * inv, o[i][3] * inv);
    *(float4*)(ctx + (size_t)(b * SEQ + s0 + r0 + i) * EMBED + h * HDIM + n0) = ov;
  }
}

// ---------------------------------------------------------------------------
// out = LayerNorm(a + r) * g + be   (one block per token, 1024 dims)
__global__ __launch_bounds__(256, 4)
void add_ln(const float* __restrict__ a, const float* __restrict__ r,
            const float* __restrict__ g, const float* __restrict__ be,
            float* __restrict__ out) {
  const int t = blockIdx.x;
  const int tid = threadIdx.x;
  const size_t base = (size_t)t * EMBED + tid * 4;
  float4 av = *(const float4*)(a + base);
  float4 rv = *(const float4*)(r + base);
  const float x0 = av.x + rv.x, x1 = av.y + rv.y;
  const float x2 = av.z + rv.z, x3 = av.w + rv.w;
  float s1 = x0 + x1 + x2 + x3;
  float s2 = x0 * x0 + x1 * x1 + x2 * x2 + x3 * x3;
  for (int off = 1; off < 64; off <<= 1) {
    s1 += __shfl_xor(s1, off);
    s2 += __shfl_xor(s2, off);
  }
  __shared__ float red[8];
  if ((tid & 63) == 0) { red[(tid >> 6) * 2] = s1; red[(tid >> 6) * 2 + 1] = s2; }
  __syncthreads();
  s1 = red[0] + red[2] + red[4] + red[6];
  s2 = red[1] + red[3] + red[5] + red[7];
  const float mu = s1 * (1.f / EMBED);
  const float var = s2 * (1.f / EMBED) - mu * mu;
  const float rstd = rsqrtf(var + 1e-6f);
  float4 gv = *(const float4*)(g + tid * 4);
  float4 bv = *(const float4*)(be + tid * 4);
  float4 ov;
  ov.x = (x0 - mu) * rstd * gv.x + bv.x;
  ov.y = (x1 - mu) * rstd * gv.y + bv.y;
  ov.z = (x2 - mu) * rstd * gv.z + bv.z;
  ov.w = (x3 - mu) * rstd * gv.w + bv.w;
  *(float4*)(out + base) = ov;
}

// ---------------------------------------------------------------------------
extern "C" void kernel_launch(void* const* d_in, const int* in_sizes, int n_in,
                              void* d_out, int out_size, void* d_ws, size_t ws_size,
                              hipStream_t stream) {
  const float* x     = (const float*)d_in[0];
  const float* Wq    = (const float*)d_in[1];
  const float* bq    = (const float*)d_in[2];
  const float* Wk    = (const float*)d_in[3];
  const float* bk    = (const float*)d_in[4];
  const float* Wv    = (const float*)d_in[5];
  const float* bv    = (const float*)d_in[6];
  const float* Wo    = (const float*)d_in[7];
  const float* bo    = (const float*)d_in[8];
  const float* ln1g  = (const float*)d_in[9];
  const float* ln1b  = (const float*)d_in[10];
  const float* W1    = (const float*)d_in[11];
  const float* b1    = (const float*)d_in[12];
  const float* W2    = (const float*)d_in[13];
  const float* b2    = (const float*)d_in[14];
  const float* ln2g  = (const float*)d_in[15];
  const float* ln2b  = (const float*)d_in[16];
  float* out = (float*)d_out;

  // workspace layout (fp32 elements); buffers reused once dead:
  //   [0..TE)    q      -> later hid (part)
  //   [TE..2TE)  k      -> later hid
  //   [2TE..3TE) v      -> later hid
  //   [3TE..4TE) ctx    -> later hid
  //   [4TE..5TE) attn_out -> later ffn_out
  //   [5TE..6TE) x1
  // total 6*TE*4B = 96 MB
  const size_t TE = (size_t)TOK * EMBED;
  float* ws  = (float*)d_ws;
  float* q   = ws;
  float* kbuf= ws + TE;
  float* vbuf= ws + 2 * TE;
  float* ctx = ws + 3 * TE;
  float* ao  = ws + 4 * TE;
  float* x1  = ws + 5 * TE;
  float* hid = ws;            // TOK x HIDDEN, overlaps dead q/k/v/ctx
  float* ffn = ao;            // overlaps dead attn_out

  const dim3 blk(256);
  const dim3 gE(EMBED / 128, TOK / 128);    // N=1024 tiles
  const dim3 gH(HIDDEN / 128, TOK / 128);   // N=4096 tiles

  gemm_bias<0><<<gE, blk, 0, stream>>>(x, Wq, bq, q,    TOK, EMBED, EMBED);
  gemm_bias<0><<<gE, blk, 0, stream>>>(x, Wk, bk, kbuf, TOK, EMBED, EMBED);
  gemm_bias<0><<<gE, blk, 0, stream>>>(x, Wv, bv, vbuf, TOK, EMBED, EMBED);

  attention<<<dim3(SEQ / 64, BATCH * HEADS), blk, 0, stream>>>(q, kbuf, vbuf, ctx);

  gemm_bias<0><<<gE, blk, 0, stream>>>(ctx, Wo, bo, ao, TOK, EMBED, EMBED);
  add_ln<<<dim3(TOK), blk, 0, stream>>>(x, ao, ln1g, ln1b, x1);

  gemm_bias<1><<<gH, blk, 0, stream>>>(x1, W1, b1, hid, TOK, EMBED, HIDDEN);
  gemm_bias<0><<<gE, blk, 0, stream>>>(hid, W2, b2, ffn, TOK, HIDDEN, EMBED);
  add_ln<<<dim3(TOK), blk, 0, stream>>>(x1, ffn, ln2g, ln2b, out);
}

// Round 2
// 563.827 us; speedup vs baseline: 3.9886x; 3.9886x over previous
//
#include <hip/hip_runtime.h>
#include <math.h>

#define EMBED 1024
#define HEADS 16
#define HDIM  64
#define HIDDEN 4096
#define BATCH 2
#define SEQ   2048
#define TOK   (BATCH * SEQ)   // 4096 tokens

typedef _Float16 f16;
typedef f16 f16x8 __attribute__((ext_vector_type(8)));
typedef f16 f16x4 __attribute__((ext_vector_type(4)));
typedef float f32x4 __attribute__((ext_vector_type(4)));

// async global->LDS, 16B per lane. LDS dest = wave-uniform base + lane*16.
__device__ __forceinline__ void gload16(const void* g, void* s) {
  __builtin_amdgcn_global_load_lds(
      (const __attribute__((address_space(1))) unsigned int*)g,
      (__attribute__((address_space(3))) unsigned int*)s, 16, 0, 0);
}

// ---------------------------------------------------------------------------
// fp16 MFMA GEMM: C[M,N] = act((A[M,K] @ W[K,N] + bias) * scale)
// W given pre-transposed+fp16 as Wt[N][K]. 128x128 tile, BK=32, 4 waves,
// wave = 64x64 = 4x4 frags of 16x16x32. LDS layout unit u = ks*128+(row^ks),
// 8 f16 per unit -> conflict-free ds_read_b128 and linear global_load_lds.
// A16: A is f16 (use global_load_lds); else fp32 (reg-stage + convert).
template<int A16, int RELU, int OUT16, int QKV>
__global__ __launch_bounds__(256, 2)
void gemm_f16(const void* __restrict__ Av, const f16* __restrict__ Wt,
              const float* __restrict__ bias0, const float* __restrict__ bias1,
              const float* __restrict__ bias2, void* __restrict__ Cv,
              int N, int K, int nbx) {
  __shared__ f16 As[512 * 8];
  __shared__ f16 Bs[512 * 8];
  const int tid = threadIdx.x;
  const int l = tid & 63, w = tid >> 6;
  const int g = l >> 4, ln = l & 15;
  // XCD-aware swizzle (gridDim.x % 8 == 0 for all our grids)
  int bid = blockIdx.x;
  const int cpx = gridDim.x >> 3;
  bid = (bid & 7) * cpx + (bid >> 3);
  const int m0 = (bid / nbx) << 7;
  const int n0 = (bid % nbx) << 7;
  const int wr = w >> 1, wc = w & 1;

  f32x4 acc[4][4] = {};

  for (int k0 = 0; k0 < K; k0 += 32) {
    // ---- stage A tile (128 rows x 32 k)
    if (A16) {
      const f16* A = (const f16*)Av;
#pragma unroll
      for (int p = 0; p < 2; ++p) {
        const int u0 = p * 256 + w * 64;
        const int ks = u0 >> 7;
        const int row = ((u0 + l) & 127) ^ ks;
        gload16(A + (size_t)(m0 + row) * K + k0 + ks * 8, (void*)&As[u0 * 8]);
      }
    } else {
      const float* A = (const float*)Av;
      const int ks = tid & 3;
      const int r0 = tid >> 2;
#pragma unroll
      for (int p = 0; p < 2; ++p) {
        const int row = r0 + p * 64;
        const float* src = A + (size_t)(m0 + row) * K + k0 + ks * 8;
        float4 f0 = *(const float4*)src;
        float4 f1 = *(const float4*)(src + 4);
        f16x8 hh;
        hh[0] = (f16)f0.x; hh[1] = (f16)f0.y; hh[2] = (f16)f0.z; hh[3] = (f16)f0.w;
        hh[4] = (f16)f1.x; hh[5] = (f16)f1.y; hh[6] = (f16)f1.z; hh[7] = (f16)f1.w;
        *(f16x8*)&As[(ks * 128 + (row ^ ks)) * 8] = hh;
      }
    }
    // ---- stage B tile from Wt[N][K] (always f16, direct-to-LDS)
#pragma unroll
    for (int p = 0; p < 2; ++p) {
      const int u0 = p * 256 + w * 64;
      const int ks = u0 >> 7;
      const int col = ((u0 + l) & 127) ^ ks;
      gload16(Wt + (size_t)(n0 + col) * K + k0 + ks * 8, (void*)&Bs[u0 * 8]);
    }
    __syncthreads();
    // ---- fragments + MFMA
    f16x8 af[4], bf[4];
#pragma unroll
    for (int m = 0; m < 4; ++m)
      af[m] = *(const f16x8*)&As[(g * 128 + ((wr * 64 + m * 16 + ln) ^ g)) * 8];
#pragma unroll
    for (int n = 0; n < 4; ++n)
      bf[n] = *(const f16x8*)&Bs[(g * 128 + ((wc * 64 + n * 16 + ln) ^ g)) * 8];
#pragma unroll
    for (int m = 0; m < 4; ++m)
#pragma unroll
      for (int n = 0; n < 4; ++n)
        acc[m][n] = __builtin_amdgcn_mfma_f32_16x16x32_f16(af[m], bf[n], acc[m][n], 0, 0, 0);
    __syncthreads();
  }

  // ---- epilogue: bias (+scale for q-part) (+relu), write f32 or f16
  const float* bp = bias0;
  int nbase = n0;
  float scale = 1.f;
  if (QKV) {
    const int seg = n0 >> 10;               // 0:q 1:k 2:v (uniform per block)
    bp = (seg == 0) ? bias0 : (seg == 1) ? bias1 : bias2;
    nbase = n0 & 1023;
    if (seg == 0) scale = 0.125f * 1.44269504f;  // 1/sqrt(64) * log2(e)
  }
  float bv[4];
#pragma unroll
  for (int n = 0; n < 4; ++n) bv[n] = bp[nbase + wc * 64 + n * 16 + ln];
#pragma unroll
  for (int m = 0; m < 4; ++m)
#pragma unroll
    for (int n = 0; n < 4; ++n)
#pragma unroll
      for (int r = 0; r < 4; ++r) {
        float v = (acc[m][n][r] + bv[n]) * scale;
        if (RELU) v = fmaxf(v, 0.f);
        const size_t idx = (size_t)(m0 + wr * 64 + m * 16 + g * 4 + r) * N
                         + n0 + wc * 64 + n * 16 + ln;
        if (OUT16) ((f16*)Cv)[idx] = (f16)v;
        else       ((float*)Cv)[idx] = v;
      }
}

// ---------------------------------------------------------------------------
// Flash attention, fp16 MFMA, fp32 accum/softmax (exp2 domain; q pre-scaled
// by 0.125*log2e in the QKV epilogue). qkv layout [t][3072] = q|k|v.
// Block = 128 q-rows of one (b,h); 4 waves x 32 rows. KV tile = 64.
__global__ __launch_bounds__(256, 2)
void attention(const f16* __restrict__ qkv, f16* __restrict__ ctx) {
  __shared__ f16 Ks[8 * 64 * 8];        // unit(ks,key): K[key][ks*8+b]
  __shared__ f16 Vs[8 * 64 * 8];        // unit(vks, d^swz): V[vks*8+b][d]
  __shared__ f16 Ps[4 * 8 * 33 * 8];    // per-wave: unit(pks,row'): P[row][pks*8+b]
  const int tid = threadIdx.x;
  const int l = tid & 63, w = tid >> 6;
  const int g = l >> 4, ln = l & 15;
  const int lnsw = ln ^ ((ln & 8) >> 2);
  const int bh = blockIdx.y;
  const int b = bh >> 4, h = bh & 15;
  const int q0 = blockIdx.x * 128;
  f16* Psw = &Ps[w * (8 * 33 * 8)];

  // Q fragments (held in registers for the whole block)
  f16x8 qf[2][2];
#pragma unroll
  for (int mi = 0; mi < 2; ++mi)
#pragma unroll
    for (int kk = 0; kk < 2; ++kk)
      qf[mi][kk] = *(const f16x8*)(qkv
          + (size_t)(b * SEQ + q0 + w * 32 + mi * 16 + ln) * 3072
          + h * 64 + kk * 32 + g * 8);

  float mrow[2][4], lrow[2][4];
  f32x4 o[2][4] = {};
#pragma unroll
  for (int mi = 0; mi < 2; ++mi)
#pragma unroll
    for (int r = 0; r < 4; ++r) { mrow[mi][r] = -1e30f; lrow[mi][r] = 0.f; }

  const int vkey = tid >> 2, vd0 = (tid & 3) * 16;
  const int vks = vkey >> 3, vb = vkey & 7;
  const int vx = ((vd0 >> 4) * 2) ^ (vks & 1);   // d-unit XOR swizzle

  for (int kt = 0; kt < SEQ / 64; ++kt) {
    // V loads (regs; transposed scatter into LDS)
    const f16* vsrc = qkv + (size_t)(b * SEQ + kt * 64 + vkey) * 3072
                    + 2048 + h * 64 + vd0;
    f16x8 v0 = *(const f16x8*)vsrc;
    f16x8 v1 = *(const f16x8*)(vsrc + 8);
    // K direct-to-LDS
#pragma unroll
    for (int t = 0; t < 2; ++t) {
      const int ks = w * 2 + t;
      gload16(qkv + (size_t)(b * SEQ + kt * 64 + l) * 3072 + 1024 + h * 64 + ks * 8,
              (void*)&Ks[ks * 64 * 8]);
    }
#pragma unroll
    for (int j = 0; j < 8; ++j)
      Vs[(vks * 64 + ((vd0 + j) ^ vx)) * 8 + vb] = v0[j];
#pragma unroll
    for (int j = 0; j < 8; ++j)
      Vs[(vks * 64 + ((vd0 + 8 + j) ^ vx)) * 8 + vb] = v1[j];
    __syncthreads();

    // ---- scores S = q.K^T (q pre-scaled)
    f32x4 s[2][4] = {};
#pragma unroll
    for (int kk = 0; kk < 2; ++kk)
#pragma unroll
      for (int n = 0; n < 4; ++n) {
        f16x8 kf = *(const f16x8*)&Ks[((kk * 4 + g) * 64 + n * 16 + ln) * 8];
#pragma unroll
        for (int mi = 0; mi < 2; ++mi)
          s[mi][n] = __builtin_amdgcn_mfma_f32_16x16x32_f16(qf[mi][kk], kf, s[mi][n], 0, 0, 0);
      }

    // ---- online softmax (exp2 domain) + P -> LDS (f16)
#pragma unroll
    for (int mi = 0; mi < 2; ++mi)
#pragma unroll
      for (int r = 0; r < 4; ++r) {
        float mt = fmaxf(fmaxf(s[mi][0][r], s[mi][1][r]), fmaxf(s[mi][2][r], s[mi][3][r]));
        mt = fmaxf(mt, __shfl_xor(mt, 1));
        mt = fmaxf(mt, __shfl_xor(mt, 2));
        mt = fmaxf(mt, __shfl_xor(mt, 4));
        mt = fmaxf(mt, __shfl_xor(mt, 8));
        const float mo = mrow[mi][r];
        const float mn = fmaxf(mo, mt);
        const float al = exp2f(mo - mn);
        mrow[mi][r] = mn;
        const int g4r = g * 4 + r;
        const int rw = mi * 16 + (g4r ^ ((g4r & 8) >> 2));
        float ps = 0.f;
#pragma unroll
        for (int n = 0; n < 4; ++n) {
          const float p = exp2f(s[mi][n][r] - mn);
          ps += p;
          Psw[((n * 2 + (ln >> 3)) * 33 + rw) * 8 + (ln & 7)] = (f16)p;
        }
        ps += __shfl_xor(ps, 1);
        ps += __shfl_xor(ps, 2);
        ps += __shfl_xor(ps, 4);
        ps += __shfl_xor(ps, 8);
        lrow[mi][r] = lrow[mi][r] * al + ps;
#pragma unroll
        for (int dj = 0; dj < 4; ++dj) o[mi][dj][r] *= al;
      }
    __syncthreads();   // P visible

    // ---- PV: O += P @ V
#pragma unroll
    for (int kk = 0; kk < 2; ++kk) {
      f16x8 pf[2];
#pragma unroll
      for (int mi = 0; mi < 2; ++mi)
        pf[mi] = *(const f16x8*)&Psw[((kk * 4 + g) * 33 + mi * 16 + lnsw) * 8];
#pragma unroll
      for (int dj = 0; dj < 4; ++dj) {
        const int k2 = kk * 4 + g;
        f16x8 vf = *(const f16x8*)&Vs[(k2 * 64 + ((dj * 16 + ln) ^ (2 * dj) ^ (k2 & 1))) * 8];
#pragma unroll
        for (int mi = 0; mi < 2; ++mi)
          o[mi][dj] = __builtin_amdgcn_mfma_f32_16x16x32_f16(pf[mi], vf, o[mi][dj], 0, 0, 0);
      }
    }
    __syncthreads();   // done reading Ks/Vs/Ps
  }

  // ---- write ctx (f16, consumed by Wo GEMM)
#pragma unroll
  for (int mi = 0; mi < 2; ++mi)
#pragma unroll
    for (int r = 0; r < 4; ++r) {
      const float inv = 1.f / lrow[mi][r];
#pragma unroll
      for (int dj = 0; dj < 4; ++dj)
        ctx[(size_t)(b * SEQ + q0 + w * 32 + mi * 16 + g * 4 + r) * EMBED
            + h * 64 + dj * 16 + ln] = (f16)(o[mi][dj][r] * inv);
    }
}

// ---------------------------------------------------------------------------
// out = LayerNorm(a + r) * g + be; optional f16 copy for next GEMM input
template<int OUT16>
__global__ __launch_bounds__(256, 4)
void add_ln(const float* __restrict__ a, const float* __restrict__ r,
            const float* __restrict__ gam, const float* __restrict__ bet,
            float* __restrict__ out, f16* __restrict__ out16) {
  const int t = blockIdx.x;
  const int tid = threadIdx.x;
  const size_t base = (size_t)t * EMBED + tid * 4;
  float4 av = *(const float4*)(a + base);
  float4 rv = *(const float4*)(r + base);
  const float x0 = av.x + rv.x, x1 = av.y + rv.y;
  const float x2 = av.z + rv.z, x3 = av.w + rv.w;
  float s1 = x0 + x1 + x2 + x3;
  float s2 = x0 * x0 + x1 * x1 + x2 * x2 + x3 * x3;
  for (int off = 1; off < 64; off <<= 1) {
    s1 += __shfl_xor(s1, off);
    s2 += __shfl_xor(s2, off);
  }
  __shared__ float red[8];
  if ((tid & 63) == 0) { red[(tid >> 6) * 2] = s1; red[(tid >> 6) * 2 + 1] = s2; }
  __syncthreads();
  s1 = red[0] + red[2] + red[4] + red[6];
  s2 = red[1] + red[3] + red[5] + red[7];
  const float mu = s1 * (1.f / EMBED);
  const float var = s2 * (1.f / EMBED) - mu * mu;
  const float rstd = rsqrtf(var + 1e-6f);
  float4 gv = *(const float4*)(gam + tid * 4);
  float4 bv = *(const float4*)(bet + tid * 4);
  float4 ov;
  ov.x = (x0 - mu) * rstd * gv.x + bv.x;
  ov.y = (x1 - mu) * rstd * gv.y + bv.y;
  ov.z = (x2 - mu) * rstd * gv.z + bv.z;
  ov.w = (x3 - mu) * rstd * gv.w + bv.w;
  *(float4*)(out + base) = ov;
  if (OUT16) {
    f16x4 hh;
    hh[0] = (f16)ov.x; hh[1] = (f16)ov.y; hh[2] = (f16)ov.z; hh[3] = (f16)ov.w;
    *(f16x4*)(out16 + base) = hh;
  }
}

// ---------------------------------------------------------------------------
// Wt[N][K] f16 = transpose(in[K][N] f32); 32x32 tiles
__global__ __launch_bounds__(256, 4)
void transpose_w(const float* __restrict__ in, f16* __restrict__ out,
                 int K, int N) {
  __shared__ float t[32][33];
  const int tid = threadIdx.x;
  const int k0 = blockIdx.y * 32, n0 = blockIdx.x * 32;
  {
    const int ky = tid >> 3, nx = (tid & 7) * 4;
    float4 f = *(const float4*)(in + (size_t)(k0 + ky) * N + n0 + nx);
    t[ky][nx] = f.x; t[ky][nx + 1] = f.y; t[ky][nx + 2] = f.z; t[ky][nx + 3] = f.w;
  }
  __syncthreads();
  const int ny = tid >> 3, kx = (tid & 7) * 4;
  f16x4 hh;
  hh[0] = (f16)t[kx][ny];     hh[1] = (f16)t[kx + 1][ny];
  hh[2] = (f16)t[kx + 2][ny]; hh[3] = (f16)t[kx + 3][ny];
  *(f16x4*)(out + (size_t)(n0 + ny) * K + k0 + kx) = hh;
}

// ---------------------------------------------------------------------------
extern "C" void kernel_launch(void* const* d_in, const int* in_sizes, int n_in,
                              void* d_out, int out_size, void* d_ws, size_t ws_size,
                              hipStream_t stream) {
  const float* x    = (const float*)d_in[0];
  const float* Wq   = (const float*)d_in[1];
  const float* bq   = (const float*)d_in[2];
  const float* Wk   = (const float*)d_in[3];
  const float* bk   = (const float*)d_in[4];
  const float* Wv   = (const float*)d_in[5];
  const float* bv   = (const float*)d_in[6];
  const float* Wo   = (const float*)d_in[7];
  const float* bo   = (const float*)d_in[8];
  const float* ln1g = (const float*)d_in[9];
  const float* ln1b = (const float*)d_in[10];
  const float* W1   = (const float*)d_in[11];
  const float* b1   = (const float*)d_in[12];
  const float* W2   = (const float*)d_in[13];
  const float* b2   = (const float*)d_in[14];
  const float* ln2g = (const float*)d_in[15];
  const float* ln2b = (const float*)d_in[16];
  float* out = (float*)d_out;

  // workspace (96 MB):
  //  0: WtQKV f16 6MB | 6: WtO 2MB | 8: Wt1 8MB | 16: Wt2 8MB
  // 24: qkv f16 24MB (later hid f16 32MB over qkv+ctx) | 48: ctx f16 8MB
  // 56: ao/ffn f32 16MB | 72: x1 f32 16MB | 88: x1h f16 8MB
  char* ws = (char*)d_ws;
  const size_t MB = 1024 * 1024;
  f16*   WtQKV = (f16*)(ws);
  f16*   WtO   = (f16*)(ws + 6 * MB);
  f16*   Wt1   = (f16*)(ws + 8 * MB);
  f16*   Wt2   = (f16*)(ws + 16 * MB);
  f16*   qkv   = (f16*)(ws + 24 * MB);
  f16*   ctx   = (f16*)(ws + 48 * MB);
  float* ao    = (float*)(ws + 56 * MB);
  float* x1    = (float*)(ws + 72 * MB);
  f16*   x1h   = (f16*)(ws + 88 * MB);
  f16*   hid   = (f16*)(ws + 24 * MB);
  float* ffn   = ao;

  const dim3 blk(256);
  transpose_w<<<dim3(32, 32), blk, 0, stream>>>(Wq, WtQKV, 1024, 1024);
  transpose_w<<<dim3(32, 32), blk, 0, stream>>>(Wk, WtQKV + 1024 * 1024, 1024, 1024);
  transpose_w<<<dim3(32, 32), blk, 0, stream>>>(Wv, WtQKV + 2 * 1024 * 1024, 1024, 1024);
  transpose_w<<<dim3(32, 32), blk, 0, stream>>>(Wo, WtO, 1024, 1024);
  transpose_w<<<dim3(128, 32), blk, 0, stream>>>(W1, Wt1, 1024, 4096);
  transpose_w<<<dim3(32, 128), blk, 0, stream>>>(W2, Wt2, 4096, 1024);

  gemm_f16<0, 0, 1, 1><<<768, blk, 0, stream>>>(x, WtQKV, bq, bk, bv, qkv, 3072, 1024, 24);
  attention<<<dim3(16, 32), blk, 0, stream>>>(qkv, ctx);
  gemm_f16<1, 0, 0, 0><<<256, blk, 0, stream>>>(ctx, WtO, bo, nullptr, nullptr, ao, 1024, 1024, 8);
  add_ln<1><<<4096, blk, 0, stream>>>(x, ao, ln1g, ln1b, x1, x1h);
  gemm_f16<1, 1, 1, 0><<<1024, blk, 0, stream>>>(x1h, Wt1, b1, nullptr, nullptr, hid, 4096, 1024, 32);
  gemm_f16<1, 0, 0, 0><<<256, blk, 0, stream>>>(hid, Wt2, b2, nullptr, nullptr, ffn, 1024, 4096, 8);
  add_ln<0><<<4096, blk, 0, stream>>>(x1, ffn, ln2g, ln2b, out, nullptr);
}

// Round 3
// 502.029 us; speedup vs baseline: 4.4796x; 1.1231x over previous
//
#include <hip/hip_runtime.h>
#include <math.h>

#define EMBED 1024
#define HEADS 16
#define HDIM  64
#define HIDDEN 4096
#define BATCH 2
#define SEQ   2048
#define TOK   (BATCH * SEQ)   // 4096 tokens

typedef _Float16 f16;
typedef f16 f16x8 __attribute__((ext_vector_type(8)));
typedef f16 f16x4 __attribute__((ext_vector_type(4)));
typedef f16 f16x2 __attribute__((ext_vector_type(2)));
typedef float f32x4 __attribute__((ext_vector_type(4)));
typedef float f32x16 __attribute__((ext_vector_type(16)));

// async global->LDS, 16B per lane. LDS dest = wave-uniform base + lane*16.
__device__ __forceinline__ void gload16(const void* g, void* s) {
  __builtin_amdgcn_global_load_lds(
      (const __attribute__((address_space(1))) unsigned int*)g,
      (__attribute__((address_space(3))) unsigned int*)s, 16, 0, 0);
}

// ---------------------------------------------------------------------------
// fp16 MFMA GEMM: C[M,N] = act((A[M,K] @ W[K,N] + bias) * scale)
// W given pre-transposed+fp16 as Wt[N][K]. 128x128 tile, BK=32, 4 waves,
// wave = 64x64 = 4x4 frags of 16x16x32. (unchanged from round 2)
template<int A16, int RELU, int OUT16, int QKV>
__global__ __launch_bounds__(256, 2)
void gemm_f16(const void* __restrict__ Av, const f16* __restrict__ Wt,
              const float* __restrict__ bias0, const float* __restrict__ bias1,
              const float* __restrict__ bias2, void* __restrict__ Cv,
              int N, int K, int nbx) {
  __shared__ f16 As[512 * 8];
  __shared__ f16 Bs[512 * 8];
  const int tid = threadIdx.x;
  const int l = tid & 63, w = tid >> 6;
  const int g = l >> 4, ln = l & 15;
  int bid = blockIdx.x;
  const int cpx = gridDim.x >> 3;
  bid = (bid & 7) * cpx + (bid >> 3);
  const int m0 = (bid / nbx) << 7;
  const int n0 = (bid % nbx) << 7;
  const int wr = w >> 1, wc = w & 1;

  f32x4 acc[4][4] = {};

  for (int k0 = 0; k0 < K; k0 += 32) {
    if (A16) {
      const f16* A = (const f16*)Av;
#pragma unroll
      for (int p = 0; p < 2; ++p) {
        const int u0 = p * 256 + w * 64;
        const int ks = u0 >> 7;
        const int row = ((u0 + l) & 127) ^ ks;
        gload16(A + (size_t)(m0 + row) * K + k0 + ks * 8, (void*)&As[u0 * 8]);
      }
    } else {
      const float* A = (const float*)Av;
      const int ks = tid & 3;
      const int r0 = tid >> 2;
#pragma unroll
      for (int p = 0; p < 2; ++p) {
        const int row = r0 + p * 64;
        const float* src = A + (size_t)(m0 + row) * K + k0 + ks * 8;
        float4 f0 = *(const float4*)src;
        float4 f1 = *(const float4*)(src + 4);
        f16x8 hh;
        hh[0] = (f16)f0.x; hh[1] = (f16)f0.y; hh[2] = (f16)f0.z; hh[3] = (f16)f0.w;
        hh[4] = (f16)f1.x; hh[5] = (f16)f1.y; hh[6] = (f16)f1.z; hh[7] = (f16)f1.w;
        *(f16x8*)&As[(ks * 128 + (row ^ ks)) * 8] = hh;
      }
    }
#pragma unroll
    for (int p = 0; p < 2; ++p) {
      const int u0 = p * 256 + w * 64;
      const int ks = u0 >> 7;
      const int col = ((u0 + l) & 127) ^ ks;
      gload16(Wt + (size_t)(n0 + col) * K + k0 + ks * 8, (void*)&Bs[u0 * 8]);
    }
    __syncthreads();
    f16x8 af[4], bf[4];
#pragma unroll
    for (int m = 0; m < 4; ++m)
      af[m] = *(const f16x8*)&As[(g * 128 + ((wr * 64 + m * 16 + ln) ^ g)) * 8];
#pragma unroll
    for (int n = 0; n < 4; ++n)
      bf[n] = *(const f16x8*)&Bs[(g * 128 + ((wc * 64 + n * 16 + ln) ^ g)) * 8];
#pragma unroll
    for (int m = 0; m < 4; ++m)
#pragma unroll
      for (int n = 0; n < 4; ++n)
        acc[m][n] = __builtin_amdgcn_mfma_f32_16x16x32_f16(af[m], bf[n], acc[m][n], 0, 0, 0);
    __syncthreads();
  }

  const float* bp = bias0;
  int nbase = n0;
  float scale = 1.f;
  if (QKV) {
    const int seg = n0 >> 10;
    bp = (seg == 0) ? bias0 : (seg == 1) ? bias1 : bias2;
    nbase = n0 & 1023;
    if (seg == 0) scale = 0.125f * 1.44269504f;  // 1/sqrt(64) * log2(e)
  }
  float bv[4];
#pragma unroll
  for (int n = 0; n < 4; ++n) bv[n] = bp[nbase + wc * 64 + n * 16 + ln];
#pragma unroll
  for (int m = 0; m < 4; ++m)
#pragma unroll
    for (int n = 0; n < 4; ++n)
#pragma unroll
      for (int r = 0; r < 4; ++r) {
        float v = (acc[m][n][r] + bv[n]) * scale;
        if (RELU) v = fmaxf(v, 0.f);
        const size_t idx = (size_t)(m0 + wr * 64 + m * 16 + g * 4 + r) * N
                         + n0 + wc * 64 + n * 16 + ln;
        if (OUT16) ((f16*)Cv)[idx] = (f16)v;
        else       ((float*)Cv)[idx] = v;
      }
}

// ---------------------------------------------------------------------------
// Flash attention, swapped-QK^T structure (fp16 MFMA 32x32x16, fp32 softmax).
// qkv layout [t][3072] = q|k|v; q pre-scaled by 0.125*log2e.
// Block = 128 q-rows of one (b,h); 4 waves x 32 q-rows. KV tile = 64.
//
// S^T = mfma(Kfrag, Qfrag): lane l holds S[key=(r&3)+8*(r>>2)+4*hi + 32*kb]
// [qrow = l&31]  ->  softmax state (m,l,alpha) is LANE-LOCAL.
// PV computed transposed: O^T = mfma(VTfrag, Pfrag); the PV contraction's
// key order is DEFINED as the S^T register order (MFMA is k-permutation
// invariant as long as A and B agree per-lane), so P needs NO cross-lane
// redistribution: pf element j <-> key 16*s + (j&3)+8*(j>>2)+4*hi, and V^T
// is read from LDS in that same order (two b64 reads per fragment).
__device__ __forceinline__ unsigned kchunk(int key, int m) { return (unsigned)(m ^ (key & 7)); }

template<int BASE>
__device__ __forceinline__ f16x8 pack_frag(f32x16 p) {
  f16x8 r;
#pragma unroll
  for (int j = 0; j < 8; ++j) r[j] = (f16)p[BASE + j];
  return r;
}

#define VSTRIDE 68   // padded V^T row stride (f16) — keeps 8B alignment, spreads banks

__global__ __launch_bounds__(256, 2)
void attention(const f16* __restrict__ qkv, f16* __restrict__ ctx) {
  __shared__ f16 Ks[64 * 64];          // unit u=key*8+c : K[key][8*(c^(key&7))+0..7]
  __shared__ f16 VT[64 * VSTRIDE];     // VT[d*VSTRIDE + key] = V[key][d]
  const int tid = threadIdx.x;
  const int l = tid & 63, w = tid >> 6;
  const int ln = l & 31, hi = l >> 5;
  const int bh = blockIdx.y, b = bh >> 4, h = bh & 15;
  const int q0 = blockIdx.x * 128;

  // Q B-fragments (held whole kernel): Q[qrow][kc*16 + hi*8 + j]
  f16x8 qf[4];
  {
    const f16* qp = qkv + (size_t)(b * SEQ + q0 + w * 32 + ln) * 3072 + h * 64 + hi * 8;
#pragma unroll
    for (int kc = 0; kc < 4; ++kc) qf[kc] = *(const f16x8*)(qp + kc * 16);
  }

  f32x16 o0 = {}, o1 = {};
  float mrow = -1e30f, lrow = 0.f;

  const int skey = tid >> 3, sc = tid & 7;   // staging: key-within-half, chunk

  for (int kt = 0; kt < SEQ / 64; ++kt) {
    const size_t tb = (size_t)(b * SEQ + kt * 64) * 3072 + h * 64;
    // ---- V -> regs (coalesced f16x8)
    f16x8 va = *(const f16x8*)(qkv + tb + 2048 + (size_t)skey * 3072 + sc * 8);
    f16x8 vb = *(const f16x8*)(qkv + tb + 2048 + (size_t)(32 + skey) * 3072 + sc * 8);
    // ---- K -> LDS direct (source pre-swizzled so LDS is linear)
#pragma unroll
    for (int p = 0; p < 2; ++p) {
      const int key = p * 32 + skey;
      gload16(qkv + tb + 1024 + (size_t)key * 3072 + 8 * kchunk(key, sc),
              (void*)&Ks[(p * 256 + w * 64) * 8]);
    }
    // ---- V^T scatter (transpose in LDS)
#pragma unroll
    for (int j = 0; j < 8; ++j) {
      const int d = sc * 8 + j;
      VT[d * VSTRIDE + skey] = va[j];
      VT[d * VSTRIDE + 32 + skey] = vb[j];
    }
    __syncthreads();

    // ---- S^T = K @ Q^T (two 32-key sub-tiles)
    f32x16 st0 = {}, st1 = {};
#pragma unroll
    for (int kc = 0; kc < 4; ++kc) {
      const int m = kc * 2 + hi;
      const f16x8 kf0 = *(const f16x8*)&Ks[(ln * 8 + (m ^ (ln & 7))) * 8];
      const f16x8 kf1 = *(const f16x8*)&Ks[((32 + ln) * 8 + (m ^ (ln & 7))) * 8];
      st0 = __builtin_amdgcn_mfma_f32_32x32x16_f16(kf0, qf[kc], st0, 0, 0, 0);
      st1 = __builtin_amdgcn_mfma_f32_32x32x16_f16(kf1, qf[kc], st1, 0, 0, 0);
    }

    // ---- online softmax, all lane-local for qrow = l&31
    float mt = st0[0];
#pragma unroll
    for (int r = 1; r < 16; ++r) mt = fmaxf(mt, st0[r]);
#pragma unroll
    for (int r = 0; r < 16; ++r) mt = fmaxf(mt, st1[r]);
    mt = fmaxf(mt, __shfl_xor(mt, 32));
    const float mn = fmaxf(mrow, mt);
    const float al = exp2f(mrow - mn);
    mrow = mn;
    float ps = 0.f;
#pragma unroll
    for (int r = 0; r < 16; ++r) { st0[r] = exp2f(st0[r] - mn); ps += st0[r]; }
#pragma unroll
    for (int r = 0; r < 16; ++r) { st1[r] = exp2f(st1[r] - mn); ps += st1[r]; }
    ps += __shfl_xor(ps, 32);
    lrow = lrow * al + ps;
#pragma unroll
    for (int r = 0; r < 16; ++r) { o0[r] *= al; o1[r] *= al; }

    // ---- P fragments: in-lane f32->f16 pack, zero cross-lane movement
    f16x8 pf[4];
    pf[0] = pack_frag<0>(st0); pf[1] = pack_frag<8>(st0);
    pf[2] = pack_frag<0>(st1); pf[3] = pack_frag<8>(st1);

    // ---- O^T += V^T @ P^T  (key order matches S^T register order)
#pragma unroll
    for (int s = 0; s < 4; ++s) {
      const int k0a = 16 * s + 4 * hi;
      {
        const f16* p0 = &VT[ln * VSTRIDE + k0a];
        f16x4 x = *(const f16x4*)p0;
        f16x4 y = *(const f16x4*)(p0 + 8);
        f16x8 vf = __builtin_shufflevector(x, y, 0, 1, 2, 3, 4, 5, 6, 7);
        o0 = __builtin_amdgcn_mfma_f32_32x32x16_f16(vf, pf[s], o0, 0, 0, 0);
      }
      {
        const f16* p1 = &VT[(32 + ln) * VSTRIDE + k0a];
        f16x4 x = *(const f16x4*)p1;
        f16x4 y = *(const f16x4*)(p1 + 8);
        f16x8 vf = __builtin_shufflevector(x, y, 0, 1, 2, 3, 4, 5, 6, 7);
        o1 = __builtin_amdgcn_mfma_f32_32x32x16_f16(vf, pf[s], o1, 0, 0, 0);
      }
    }
    __syncthreads();
  }

  // ---- write ctx (f16): O^T lane l holds d=(r&3)+8*(r>>2)+4*hi (+32 for o1),
  // qrow = l&31
  const float inv = 1.f / lrow;
  f16* cp = ctx + (size_t)(b * SEQ + q0 + w * 32 + ln) * EMBED + h * 64;
#pragma unroll
  for (int r = 0; r < 16; ++r) {
    const int drow = (r & 3) + 8 * (r >> 2) + 4 * hi;
    cp[drow] = (f16)(o0[r] * inv);
    cp[32 + drow] = (f16)(o1[r] * inv);
  }
}

// ---------------------------------------------------------------------------
// out = LayerNorm(a + r) * g + be; optional f16 copy for next GEMM input
template<int OUT16>
__global__ __launch_bounds__(256, 4)
void add_ln(const float* __restrict__ a, const float* __restrict__ r,
            const float* __restrict__ gam, const float* __restrict__ bet,
            float* __restrict__ out, f16* __restrict__ out16) {
  const int t = blockIdx.x;
  const int tid = threadIdx.x;
  const size_t base = (size_t)t * EMBED + tid * 4;
  float4 av = *(const float4*)(a + base);
  float4 rv = *(const float4*)(r + base);
  const float x0 = av.x + rv.x, x1 = av.y + rv.y;
  const float x2 = av.z + rv.z, x3 = av.w + rv.w;
  float s1 = x0 + x1 + x2 + x3;
  float s2 = x0 * x0 + x1 * x1 + x2 * x2 + x3 * x3;
  for (int off = 1; off < 64; off <<= 1) {
    s1 += __shfl_xor(s1, off);
    s2 += __shfl_xor(s2, off);
  }
  __shared__ float red[8];
  if ((tid & 63) == 0) { red[(tid >> 6) * 2] = s1; red[(tid >> 6) * 2 + 1] = s2; }
  __syncthreads();
  s1 = red[0] + red[2] + red[4] + red[6];
  s2 = red[1] + red[3] + red[5] + red[7];
  const float mu = s1 * (1.f / EMBED);
  const float var = s2 * (1.f / EMBED) - mu * mu;
  const float rstd = rsqrtf(var + 1e-6f);
  float4 gv = *(const float4*)(gam + tid * 4);
  float4 bv = *(const float4*)(bet + tid * 4);
  float4 ov;
  ov.x = (x0 - mu) * rstd * gv.x + bv.x;
  ov.y = (x1 - mu) * rstd * gv.y + bv.y;
  ov.z = (x2 - mu) * rstd * gv.z + bv.z;
  ov.w = (x3 - mu) * rstd * gv.w + bv.w;
  *(float4*)(out + base) = ov;
  if (OUT16) {
    f16x4 hh;
    hh[0] = (f16)ov.x; hh[1] = (f16)ov.y; hh[2] = (f16)ov.z; hh[3] = (f16)ov.w;
    *(f16x4*)(out16 + base) = hh;
  }
}

// ---------------------------------------------------------------------------
// Wt[N][K] f16 = transpose(in[K][N] f32); 32x32 tiles
__global__ __launch_bounds__(256, 4)
void transpose_w(const float* __restrict__ in, f16* __restrict__ out,
                 int K, int N) {
  __shared__ float t[32][33];
  const int tid = threadIdx.x;
  const int k0 = blockIdx.y * 32, n0 = blockIdx.x * 32;
  {
    const int ky = tid >> 3, nx = (tid & 7) * 4;
    float4 f = *(const float4*)(in + (size_t)(k0 + ky) * N + n0 + nx);
    t[ky][nx] = f.x; t[ky][nx + 1] = f.y; t[ky][nx + 2] = f.z; t[ky][nx + 3] = f.w;
  }
  __syncthreads();
  const int ny = tid >> 3, kx = (tid & 7) * 4;
  f16x4 hh;
  hh[0] = (f16)t[kx][ny];     hh[1] = (f16)t[kx + 1][ny];
  hh[2] = (f16)t[kx + 2][ny]; hh[3] = (f16)t[kx + 3][ny];
  *(f16x4*)(out + (size_t)(n0 + ny) * K + k0 + kx) = hh;
}

// ---------------------------------------------------------------------------
extern "C" void kernel_launch(void* const* d_in, const int* in_sizes, int n_in,
                              void* d_out, int out_size, void* d_ws, size_t ws_size,
                              hipStream_t stream) {
  const float* x    = (const float*)d_in[0];
  const float* Wq   = (const float*)d_in[1];
  const float* bq   = (const float*)d_in[2];
  const float* Wk   = (const float*)d_in[3];
  const float* bk   = (const float*)d_in[4];
  const float* Wv   = (const float*)d_in[5];
  const float* bv   = (const float*)d_in[6];
  const float* Wo   = (const float*)d_in[7];
  const float* bo   = (const float*)d_in[8];
  const float* ln1g = (const float*)d_in[9];
  const float* ln1b = (const float*)d_in[10];
  const float* W1   = (const float*)d_in[11];
  const float* b1   = (const float*)d_in[12];
  const float* W2   = (const float*)d_in[13];
  const float* b2   = (const float*)d_in[14];
  const float* ln2g = (const float*)d_in[15];
  const float* ln2b = (const float*)d_in[16];
  float* out = (float*)d_out;

  char* ws = (char*)d_ws;
  const size_t MB = 1024 * 1024;
  f16*   WtQKV = (f16*)(ws);
  f16*   WtO   = (f16*)(ws + 6 * MB);
  f16*   Wt1   = (f16*)(ws + 8 * MB);
  f16*   Wt2   = (f16*)(ws + 16 * MB);
  f16*   qkv   = (f16*)(ws + 24 * MB);
  f16*   ctx   = (f16*)(ws + 48 * MB);
  float* ao    = (float*)(ws + 56 * MB);
  float* x1    = (float*)(ws + 72 * MB);
  f16*   x1h   = (f16*)(ws + 88 * MB);
  f16*   hid   = (f16*)(ws + 24 * MB);
  float* ffn   = ao;

  const dim3 blk(256);
  transpose_w<<<dim3(32, 32), blk, 0, stream>>>(Wq, WtQKV, 1024, 1024);
  transpose_w<<<dim3(32, 32), blk, 0, stream>>>(Wk, WtQKV + 1024 * 1024, 1024, 1024);
  transpose_w<<<dim3(32, 32), blk, 0, stream>>>(Wv, WtQKV + 2 * 1024 * 1024, 1024, 1024);
  transpose_w<<<dim3(32, 32), blk, 0, stream>>>(Wo, WtO, 1024, 1024);
  transpose_w<<<dim3(128, 32), blk, 0, stream>>>(W1, Wt1, 1024, 4096);
  transpose_w<<<dim3(32, 128), blk, 0, stream>>>(W2, Wt2, 4096, 1024);

  gemm_f16<0, 0, 1, 1><<<768, blk, 0, stream>>>(x, WtQKV, bq, bk, bv, qkv, 3072, 1024, 24);
  attention<<<dim3(16, 32), blk, 0, stream>>>(qkv, ctx);
  gemm_f16<1, 0, 0, 0><<<256, blk, 0, stream>>>(ctx, WtO, bo, nullptr, nullptr, ao, 1024, 1024, 8);
  add_ln<1><<<4096, blk, 0, stream>>>(x, ao, ln1g, ln1b, x1, x1h);
  gemm_f16<1, 1, 1, 0><<<1024, blk, 0, stream>>>(x1h, Wt1, b1, nullptr, nullptr, hid, 4096, 1024, 32);
  gemm_f16<1, 0, 0, 0><<<256, blk, 0, stream>>>(hid, Wt2, b2, nullptr, nullptr, ffn, 1024, 4096, 8);
  add_ln<0><<<4096, blk, 0, stream>>>(x1, ffn, ln2g, ln2b, out, nullptr);
}

// Round 4
// 451.672 us; speedup vs baseline: 4.9790x; 1.1115x over previous
//
#include <hip/hip_runtime.h>
#include <math.h>

#define EMBED 1024
#define HEADS 16
#define HDIM  64
#define HIDDEN 4096
#define BATCH 2
#define SEQ   2048
#define TOK   (BATCH * SEQ)   // 4096 tokens

typedef _Float16 f16;
typedef f16 f16x8 __attribute__((ext_vector_type(8)));
typedef f16 f16x4 __attribute__((ext_vector_type(4)));
typedef float f32x4 __attribute__((ext_vector_type(4)));
typedef float f32x16 __attribute__((ext_vector_type(16)));

// async global->LDS, 16B per lane. LDS dest = wave-uniform base + lane*16.
__device__ __forceinline__ void gload16(const void* g, void* s) {
  __builtin_amdgcn_global_load_lds(
      (const __attribute__((address_space(1))) unsigned int*)g,
      (__attribute__((address_space(3))) unsigned int*)s, 16, 0, 0);
}

// ---------------------------------------------------------------------------
// fp16 MFMA GEMM: C[M,N] = act((A[M,K] @ W[K,N] + bias) * scale)
// W pre-transposed+fp16 as Wt[N][K]. 128x128 tile, BK=32, 4 waves,
// wave = 64x64 = 4x4 frags of 16x16x32.
// SPLITK>1: grid = ntiles*SPLITK (slice = fastest dim); each slice covers
// K/SPLITK and writes raw f32 partials to Cv + slice*TOK*N (bias/act applied
// later in add_ln).
template<int A16, int RELU, int OUT16, int QKV, int SPLITK>
__global__ __launch_bounds__(256, 3)
void gemm_f16(const void* __restrict__ Av, const f16* __restrict__ Wt,
              const float* __restrict__ bias0, const float* __restrict__ bias1,
              const float* __restrict__ bias2, void* __restrict__ Cv,
              int N, int K, int nbx) {
  __shared__ f16 As[512 * 8];
  __shared__ f16 Bs[512 * 8];
  const int tid = threadIdx.x;
  const int l = tid & 63, w = tid >> 6;
  const int g = l >> 4, ln = l & 15;
  int bid = blockIdx.x;
  int slice = 0;
  if (SPLITK > 1) { slice = bid % SPLITK; bid /= SPLITK; }
  const int ntiles = gridDim.x / SPLITK;
  const int cpx = ntiles >> 3;
  bid = (bid & 7) * cpx + (bid >> 3);     // XCD swizzle over tiles
  const int m0 = (bid / nbx) << 7;
  const int n0 = (bid % nbx) << 7;
  const int wr = w >> 1, wc = w & 1;
  const int ksl = K / SPLITK;
  const int kbeg = slice * ksl, kend = kbeg + ksl;

  f32x4 acc[4][4] = {};

  for (int k0 = kbeg; k0 < kend; k0 += 32) {
    if (A16) {
      const f16* A = (const f16*)Av;
#pragma unroll
      for (int p = 0; p < 2; ++p) {
        const int u0 = p * 256 + w * 64;
        const int ks = u0 >> 7;
        const int row = ((u0 + l) & 127) ^ ks;
        gload16(A + (size_t)(m0 + row) * K + k0 + ks * 8, (void*)&As[u0 * 8]);
      }
    } else {
      const float* A = (const float*)Av;
      const int ks = tid & 3;
      const int r0 = tid >> 2;
#pragma unroll
      for (int p = 0; p < 2; ++p) {
        const int row = r0 + p * 64;
        const float* src = A + (size_t)(m0 + row) * K + k0 + ks * 8;
        float4 f0 = *(const float4*)src;
        float4 f1 = *(const float4*)(src + 4);
        f16x8 hh;
        hh[0] = (f16)f0.x; hh[1] = (f16)f0.y; hh[2] = (f16)f0.z; hh[3] = (f16)f0.w;
        hh[4] = (f16)f1.x; hh[5] = (f16)f1.y; hh[6] = (f16)f1.z; hh[7] = (f16)f1.w;
        *(f16x8*)&As[(ks * 128 + (row ^ ks)) * 8] = hh;
      }
    }
#pragma unroll
    for (int p = 0; p < 2; ++p) {
      const int u0 = p * 256 + w * 64;
      const int ks = u0 >> 7;
      const int col = ((u0 + l) & 127) ^ ks;
      gload16(Wt + (size_t)(n0 + col) * K + k0 + ks * 8, (void*)&Bs[u0 * 8]);
    }
    __syncthreads();
    f16x8 af[4], bf[4];
#pragma unroll
    for (int m = 0; m < 4; ++m)
      af[m] = *(const f16x8*)&As[(g * 128 + ((wr * 64 + m * 16 + ln) ^ g)) * 8];
#pragma unroll
    for (int n = 0; n < 4; ++n)
      bf[n] = *(const f16x8*)&Bs[(g * 128 + ((wc * 64 + n * 16 + ln) ^ g)) * 8];
#pragma unroll
    for (int m = 0; m < 4; ++m)
#pragma unroll
      for (int n = 0; n < 4; ++n)
        acc[m][n] = __builtin_amdgcn_mfma_f32_16x16x32_f16(af[m], bf[n], acc[m][n], 0, 0, 0);
    __syncthreads();
  }

  if (SPLITK > 1) {
    float* P = (float*)Cv + (size_t)slice * TOK * N;
#pragma unroll
    for (int m = 0; m < 4; ++m)
#pragma unroll
      for (int n = 0; n < 4; ++n)
#pragma unroll
        for (int r = 0; r < 4; ++r) {
          const size_t idx = (size_t)(m0 + wr * 64 + m * 16 + g * 4 + r) * N
                           + n0 + wc * 64 + n * 16 + ln;
          P[idx] = acc[m][n][r];
        }
    return;
  }

  const float* bp = bias0;
  int nbase = n0;
  float scale = 1.f;
  if (QKV) {
    const int seg = n0 >> 10;
    bp = (seg == 0) ? bias0 : (seg == 1) ? bias1 : bias2;
    nbase = n0 & 1023;
    if (seg == 0) scale = 0.125f * 1.44269504f;  // 1/sqrt(64) * log2(e)
  }
  float bv[4];
#pragma unroll
  for (int n = 0; n < 4; ++n) bv[n] = bp[nbase + wc * 64 + n * 16 + ln];
#pragma unroll
  for (int m = 0; m < 4; ++m)
#pragma unroll
    for (int n = 0; n < 4; ++n)
#pragma unroll
      for (int r = 0; r < 4; ++r) {
        float v = (acc[m][n][r] + bv[n]) * scale;
        if (RELU) v = fmaxf(v, 0.f);
        const size_t idx = (size_t)(m0 + wr * 64 + m * 16 + g * 4 + r) * N
                         + n0 + wc * 64 + n * 16 + ln;
        if (OUT16) ((f16*)Cv)[idx] = (f16)v;
        else       ((float*)Cv)[idx] = v;
      }
}

// ---------------------------------------------------------------------------
// Flash attention, swapped-QK^T structure (fp16 MFMA 32x32x16, fp32 softmax).
// (unchanged from round 3 — verified working)
__device__ __forceinline__ unsigned kchunk(int key, int m) { return (unsigned)(m ^ (key & 7)); }

template<int BASE>
__device__ __forceinline__ f16x8 pack_frag(f32x16 p) {
  f16x8 r;
#pragma unroll
  for (int j = 0; j < 8; ++j) r[j] = (f16)p[BASE + j];
  return r;
}

#define VSTRIDE 68

__global__ __launch_bounds__(256, 2)
void attention(const f16* __restrict__ qkv, f16* __restrict__ ctx) {
  __shared__ f16 Ks[64 * 64];
  __shared__ f16 VT[64 * VSTRIDE];
  const int tid = threadIdx.x;
  const int l = tid & 63, w = tid >> 6;
  const int ln = l & 31, hi = l >> 5;
  const int bh = blockIdx.y, b = bh >> 4, h = bh & 15;
  const int q0 = blockIdx.x * 128;

  f16x8 qf[4];
  {
    const f16* qp = qkv + (size_t)(b * SEQ + q0 + w * 32 + ln) * 3072 + h * 64 + hi * 8;
#pragma unroll
    for (int kc = 0; kc < 4; ++kc) qf[kc] = *(const f16x8*)(qp + kc * 16);
  }

  f32x16 o0 = {}, o1 = {};
  float mrow = -1e30f, lrow = 0.f;

  const int skey = tid >> 3, sc = tid & 7;

  for (int kt = 0; kt < SEQ / 64; ++kt) {
    const size_t tb = (size_t)(b * SEQ + kt * 64) * 3072 + h * 64;
    f16x8 va = *(const f16x8*)(qkv + tb + 2048 + (size_t)skey * 3072 + sc * 8);
    f16x8 vb = *(const f16x8*)(qkv + tb + 2048 + (size_t)(32 + skey) * 3072 + sc * 8);
#pragma unroll
    for (int p = 0; p < 2; ++p) {
      const int key = p * 32 + skey;
      gload16(qkv + tb + 1024 + (size_t)key * 3072 + 8 * kchunk(key, sc),
              (void*)&Ks[(p * 256 + w * 64) * 8]);
    }
#pragma unroll
    for (int j = 0; j < 8; ++j) {
      const int d = sc * 8 + j;
      VT[d * VSTRIDE + skey] = va[j];
      VT[d * VSTRIDE + 32 + skey] = vb[j];
    }
    __syncthreads();

    f32x16 st0 = {}, st1 = {};
#pragma unroll
    for (int kc = 0; kc < 4; ++kc) {
      const int m = kc * 2 + hi;
      const f16x8 kf0 = *(const f16x8*)&Ks[(ln * 8 + (m ^ (ln & 7))) * 8];
      const f16x8 kf1 = *(const f16x8*)&Ks[((32 + ln) * 8 + (m ^ (ln & 7))) * 8];
      st0 = __builtin_amdgcn_mfma_f32_32x32x16_f16(kf0, qf[kc], st0, 0, 0, 0);
      st1 = __builtin_amdgcn_mfma_f32_32x32x16_f16(kf1, qf[kc], st1, 0, 0, 0);
    }

    float mt = st0[0];
#pragma unroll
    for (int r = 1; r < 16; ++r) mt = fmaxf(mt, st0[r]);
#pragma unroll
    for (int r = 0; r < 16; ++r) mt = fmaxf(mt, st1[r]);
    mt = fmaxf(mt, __shfl_xor(mt, 32));
    const float mn = fmaxf(mrow, mt);
    const float al = exp2f(mrow - mn);
    mrow = mn;
    float ps = 0.f;
#pragma unroll
    for (int r = 0; r < 16; ++r) { st0[r] = exp2f(st0[r] - mn); ps += st0[r]; }
#pragma unroll
    for (int r = 0; r < 16; ++r) { st1[r] = exp2f(st1[r] - mn); ps += st1[r]; }
    ps += __shfl_xor(ps, 32);
    lrow = lrow * al + ps;
#pragma unroll
    for (int r = 0; r < 16; ++r) { o0[r] *= al; o1[r] *= al; }

    f16x8 pf[4];
    pf[0] = pack_frag<0>(st0); pf[1] = pack_frag<8>(st0);
    pf[2] = pack_frag<0>(st1); pf[3] = pack_frag<8>(st1);

#pragma unroll
    for (int s = 0; s < 4; ++s) {
      const int k0a = 16 * s + 4 * hi;
      {
        const f16* p0 = &VT[ln * VSTRIDE + k0a];
        f16x4 x = *(const f16x4*)p0;
        f16x4 y = *(const f16x4*)(p0 + 8);
        f16x8 vf = __builtin_shufflevector(x, y, 0, 1, 2, 3, 4, 5, 6, 7);
        o0 = __builtin_amdgcn_mfma_f32_32x32x16_f16(vf, pf[s], o0, 0, 0, 0);
      }
      {
        const f16* p1 = &VT[(32 + ln) * VSTRIDE + k0a];
        f16x4 x = *(const f16x4*)p1;
        f16x4 y = *(const f16x4*)(p1 + 8);
        f16x8 vf = __builtin_shufflevector(x, y, 0, 1, 2, 3, 4, 5, 6, 7);
        o1 = __builtin_amdgcn_mfma_f32_32x32x16_f16(vf, pf[s], o1, 0, 0, 0);
      }
    }
    __syncthreads();
  }

  const float inv = 1.f / lrow;
  f16* cp = ctx + (size_t)(b * SEQ + q0 + w * 32 + ln) * EMBED + h * 64;
#pragma unroll
  for (int r = 0; r < 16; ++r) {
    const int drow = (r & 3) + 8 * (r >> 2) + 4 * hi;
    cp[drow] = (f16)(o0[r] * inv);
    cp[32 + drow] = (f16)(o1[r] * inv);
  }
}

// ---------------------------------------------------------------------------
// out = LayerNorm(resid + bias + sum_p parts[p]) * g + be
// NOTE: out may alias resid (x1 stored in d_out) — per-token self-overwrite,
// reads complete before writes within each thread; no __restrict__ on those.
template<int NP, int OUT16>
__global__ __launch_bounds__(256, 4)
void add_ln(const float* parts, const float* __restrict__ bias,
            const float* resid, const float* __restrict__ gam,
            const float* __restrict__ bet, float* out, f16* __restrict__ out16) {
  const int t = blockIdx.x;
  const int tid = threadIdx.x;
  const size_t base = (size_t)t * EMBED + tid * 4;
  float4 rv = *(const float4*)(resid + base);
  float4 bb = *(const float4*)(bias + tid * 4);
  float x0 = rv.x + bb.x, x1 = rv.y + bb.y, x2 = rv.z + bb.z, x3 = rv.w + bb.w;
#pragma unroll
  for (int p = 0; p < NP; ++p) {
    float4 pv = *(const float4*)(parts + (size_t)p * TOK * EMBED + base);
    x0 += pv.x; x1 += pv.y; x2 += pv.z; x3 += pv.w;
  }
  float s1 = x0 + x1 + x2 + x3;
  float s2 = x0 * x0 + x1 * x1 + x2 * x2 + x3 * x3;
  for (int off = 1; off < 64; off <<= 1) {
    s1 += __shfl_xor(s1, off);
    s2 += __shfl_xor(s2, off);
  }
  __shared__ float red[8];
  if ((tid & 63) == 0) { red[(tid >> 6) * 2] = s1; red[(tid >> 6) * 2 + 1] = s2; }
  __syncthreads();
  s1 = red[0] + red[2] + red[4] + red[6];
  s2 = red[1] + red[3] + red[5] + red[7];
  const float mu = s1 * (1.f / EMBED);
  const float var = s2 * (1.f / EMBED) - mu * mu;
  const float rstd = rsqrtf(var + 1e-6f);
  float4 gv = *(const float4*)(gam + tid * 4);
  float4 bv = *(const float4*)(bet + tid * 4);
  float4 ov;
  ov.x = (x0 - mu) * rstd * gv.x + bv.x;
  ov.y = (x1 - mu) * rstd * gv.y + bv.y;
  ov.z = (x2 - mu) * rstd * gv.z + bv.z;
  ov.w = (x3 - mu) * rstd * gv.w + bv.w;
  *(float4*)(out + base) = ov;
  if (OUT16) {
    f16x4 hh;
    hh[0] = (f16)ov.x; hh[1] = (f16)ov.y; hh[2] = (f16)ov.z; hh[3] = (f16)ov.w;
    *(f16x4*)(out16 + base) = hh;
  }
}

// ---------------------------------------------------------------------------
// Wt[N][K] f16 = transpose(in[K][N] f32); 32x32 tiles
__device__ __forceinline__ void transpose_tile(const float* in, f16* out,
                                               int K, int N, int k0, int n0, int tid) {
  __shared__ float t[32][33];
  {
    const int ky = tid >> 3, nx = (tid & 7) * 4;
    float4 f = *(const float4*)(in + (size_t)(k0 + ky) * N + n0 + nx);
    t[ky][nx] = f.x; t[ky][nx + 1] = f.y; t[ky][nx + 2] = f.z; t[ky][nx + 3] = f.w;
  }
  __syncthreads();
  const int ny = tid >> 3, kx = (tid & 7) * 4;
  f16x4 hh;
  hh[0] = (f16)t[kx][ny];     hh[1] = (f16)t[kx + 1][ny];
  hh[2] = (f16)t[kx + 2][ny]; hh[3] = (f16)t[kx + 3][ny];
  *(f16x4*)(out + (size_t)(n0 + ny) * K + k0 + kx) = hh;
}

__global__ __launch_bounds__(256, 4)
void transpose_w(const float* __restrict__ in, f16* __restrict__ out,
                 int K, int N) {
  transpose_tile(in, out, K, N, blockIdx.y * 32, blockIdx.x * 32, threadIdx.x);
}

// z-batched 1024x1024 transpose for Wq/Wk/Wv
__global__ __launch_bounds__(256, 4)
void transpose_qkv(const float* __restrict__ w0, const float* __restrict__ w1,
                   const float* __restrict__ w2, f16* __restrict__ out) {
  const float* in = (blockIdx.z == 0) ? w0 : (blockIdx.z == 1) ? w1 : w2;
  f16* o = out + (size_t)blockIdx.z * 1024 * 1024;
  transpose_tile(in, o, 1024, 1024, blockIdx.y * 32, blockIdx.x * 32, threadIdx.x);
}

// ---------------------------------------------------------------------------
extern "C" void kernel_launch(void* const* d_in, const int* in_sizes, int n_in,
                              void* d_out, int out_size, void* d_ws, size_t ws_size,
                              hipStream_t stream) {
  const float* x    = (const float*)d_in[0];
  const float* Wq   = (const float*)d_in[1];
  const float* bq   = (const float*)d_in[2];
  const float* Wk   = (const float*)d_in[3];
  const float* bk   = (const float*)d_in[4];
  const float* Wv   = (const float*)d_in[5];
  const float* bv   = (const float*)d_in[6];
  const float* Wo   = (const float*)d_in[7];
  const float* bo   = (const float*)d_in[8];
  const float* ln1g = (const float*)d_in[9];
  const float* ln1b = (const float*)d_in[10];
  const float* W1   = (const float*)d_in[11];
  const float* b1   = (const float*)d_in[12];
  const float* W2   = (const float*)d_in[13];
  const float* b2   = (const float*)d_in[14];
  const float* ln2g = (const float*)d_in[15];
  const float* ln2b = (const float*)d_in[16];
  float* out = (float*)d_out;

  // workspace (96 MB):
  //  0: WtQKV f16 6MB | 6: WtO 2MB | 8: Wt1 8MB | 16: Wt2 8MB
  // 24: qkv f16 24MB (later hid f16 32MB over 24-56) | 48: ctx f16 8MB
  // 56: parts f32 2x16MB (Wo partials, then W2 partials) | 88: x1h f16 8MB
  // x1 (f32) lives in d_out (overwritten by the final LN in-place).
  char* ws = (char*)d_ws;
  const size_t MB = 1024 * 1024;
  f16*   WtQKV = (f16*)(ws);
  f16*   WtO   = (f16*)(ws + 6 * MB);
  f16*   Wt1   = (f16*)(ws + 8 * MB);
  f16*   Wt2   = (f16*)(ws + 16 * MB);
  f16*   qkv   = (f16*)(ws + 24 * MB);
  f16*   ctx   = (f16*)(ws + 48 * MB);
  float* parts = (float*)(ws + 56 * MB);
  f16*   x1h   = (f16*)(ws + 88 * MB);
  f16*   hid   = (f16*)(ws + 24 * MB);
  float* x1    = out;   // d_out doubles as x1 storage

  const dim3 blk(256);
  transpose_qkv<<<dim3(32, 32, 3), blk, 0, stream>>>(Wq, Wk, Wv, WtQKV);
  transpose_w<<<dim3(32, 32), blk, 0, stream>>>(Wo, WtO, 1024, 1024);
  transpose_w<<<dim3(128, 32), blk, 0, stream>>>(W1, Wt1, 1024, 4096);
  transpose_w<<<dim3(32, 128), blk, 0, stream>>>(W2, Wt2, 4096, 1024);

  gemm_f16<0, 0, 1, 1, 1><<<768, blk, 0, stream>>>(x, WtQKV, bq, bk, bv, qkv, 3072, 1024, 24);
  attention<<<dim3(16, 32), blk, 0, stream>>>(qkv, ctx);
  gemm_f16<1, 0, 0, 0, 2><<<512, blk, 0, stream>>>(ctx, WtO, nullptr, nullptr, nullptr, parts, 1024, 1024, 8);
  add_ln<2, 1><<<4096, blk, 0, stream>>>(parts, bo, x, ln1g, ln1b, x1, x1h);
  gemm_f16<1, 1, 1, 0, 1><<<1024, blk, 0, stream>>>(x1h, Wt1, b1, nullptr, nullptr, hid, 4096, 1024, 32);
  gemm_f16<1, 0, 0, 0, 2><<<512, blk, 0, stream>>>(hid, Wt2, nullptr, nullptr, nullptr, parts, 1024, 4096, 8);
  add_ln<2, 0><<<4096, blk, 0, stream>>>(parts, b2, x1, ln2g, ln2b, out, nullptr);
}

// Round 8
// 448.134 us; speedup vs baseline: 5.0183x; 1.0079x over previous
//
#include <hip/hip_runtime.h>
#include <math.h>

#define EMBED 1024
#define HEADS 16
#define HDIM  64
#define HIDDEN 4096
#define BATCH 2
#define SEQ   2048
#define TOK   (BATCH * SEQ)   // 4096 tokens

typedef _Float16 f16;
typedef f16 f16x8 __attribute__((ext_vector_type(8)));
typedef f16 f16x4 __attribute__((ext_vector_type(4)));
typedef float f32x4 __attribute__((ext_vector_type(4)));
typedef float f32x16 __attribute__((ext_vector_type(16)));

// async global->LDS, 16B per lane. LDS dest = wave-uniform base + lane*16.
__device__ __forceinline__ void gload16(const void* g, void* s) {
  __builtin_amdgcn_global_load_lds(
      (const __attribute__((address_space(1))) unsigned int*)g,
      (__attribute__((address_space(3))) unsigned int*)s, 16, 0, 0);
}

// ---------------------------------------------------------------------------
// fp16 MFMA GEMM: C[M,N] = act((A[M,K] @ W[K,N] + bias) * scale)
// W pre-transposed+fp16 as Wt[N][K]. 128x128 tile, BK=32, 4 waves,
// wave = 64x64 = 4x4 frags of 16x16x32. SPLITK>1 writes raw f32 partials
// (bias/act applied in add_ln).  (unchanged from round 4 — verified)
template<int A16, int RELU, int OUT16, int QKV, int SPLITK>
__global__ __launch_bounds__(256, 3)
void gemm_f16(const void* __restrict__ Av, const f16* __restrict__ Wt,
              const float* __restrict__ bias0, const float* __restrict__ bias1,
              const float* __restrict__ bias2, void* __restrict__ Cv,
              int N, int K, int nbx) {
  __shared__ f16 As[512 * 8];
  __shared__ f16 Bs[512 * 8];
  const int tid = threadIdx.x;
  const int l = tid & 63, w = tid >> 6;
  const int g = l >> 4, ln = l & 15;
  int bid = blockIdx.x;
  int slice = 0;
  if (SPLITK > 1) { slice = bid % SPLITK; bid /= SPLITK; }
  const int ntiles = gridDim.x / SPLITK;
  const int cpx = ntiles >> 3;
  bid = (bid & 7) * cpx + (bid >> 3);     // XCD swizzle over tiles
  const int m0 = (bid / nbx) << 7;
  const int n0 = (bid % nbx) << 7;
  const int wr = w >> 1, wc = w & 1;
  const int ksl = K / SPLITK;
  const int kbeg = slice * ksl, kend = kbeg + ksl;

  f32x4 acc[4][4] = {};

  for (int k0 = kbeg; k0 < kend; k0 += 32) {
    if (A16) {
      const f16* A = (const f16*)Av;
#pragma unroll
      for (int p = 0; p < 2; ++p) {
        const int u0 = p * 256 + w * 64;
        const int ks = u0 >> 7;
        const int row = ((u0 + l) & 127) ^ ks;
        gload16(A + (size_t)(m0 + row) * K + k0 + ks * 8, (void*)&As[u0 * 8]);
      }
    } else {
      const float* A = (const float*)Av;
      const int ks = tid & 3;
      const int r0 = tid >> 2;
#pragma unroll
      for (int p = 0; p < 2; ++p) {
        const int row = r0 + p * 64;
        const float* src = A + (size_t)(m0 + row) * K + k0 + ks * 8;
        float4 f0 = *(const float4*)src;
        float4 f1 = *(const float4*)(src + 4);
        f16x8 hh;
        hh[0] = (f16)f0.x; hh[1] = (f16)f0.y; hh[2] = (f16)f0.z; hh[3] = (f16)f0.w;
        hh[4] = (f16)f1.x; hh[5] = (f16)f1.y; hh[6] = (f16)f1.z; hh[7] = (f16)f1.w;
        *(f16x8*)&As[(ks * 128 + (row ^ ks)) * 8] = hh;
      }
    }
#pragma unroll
    for (int p = 0; p < 2; ++p) {
      const int u0 = p * 256 + w * 64;
      const int ks = u0 >> 7;
      const int col = ((u0 + l) & 127) ^ ks;
      gload16(Wt + (size_t)(n0 + col) * K + k0 + ks * 8, (void*)&Bs[u0 * 8]);
    }
    __syncthreads();
    f16x8 af[4], bf[4];
#pragma unroll
    for (int m = 0; m < 4; ++m)
      af[m] = *(const f16x8*)&As[(g * 128 + ((wr * 64 + m * 16 + ln) ^ g)) * 8];
#pragma unroll
    for (int n = 0; n < 4; ++n)
      bf[n] = *(const f16x8*)&Bs[(g * 128 + ((wc * 64 + n * 16 + ln) ^ g)) * 8];
#pragma unroll
    for (int m = 0; m < 4; ++m)
#pragma unroll
      for (int n = 0; n < 4; ++n)
        acc[m][n] = __builtin_amdgcn_mfma_f32_16x16x32_f16(af[m], bf[n], acc[m][n], 0, 0, 0);
    __syncthreads();
  }

  if (SPLITK > 1) {
    float* P = (float*)Cv + (size_t)slice * TOK * N;
#pragma unroll
    for (int m = 0; m < 4; ++m)
#pragma unroll
      for (int n = 0; n < 4; ++n)
#pragma unroll
        for (int r = 0; r < 4; ++r) {
          const size_t idx = (size_t)(m0 + wr * 64 + m * 16 + g * 4 + r) * N
                           + n0 + wc * 64 + n * 16 + ln;
          P[idx] = acc[m][n][r];
        }
    return;
  }

  const float* bp = bias0;
  int nbase = n0;
  float scale = 1.f;
  if (QKV) {
    const int seg = n0 >> 10;
    bp = (seg == 0) ? bias0 : (seg == 1) ? bias1 : bias2;
    nbase = n0 & 1023;
    if (seg == 0) scale = 0.125f * 1.44269504f;  // 1/sqrt(64) * log2(e)
  }
  float bv[4];
#pragma unroll
  for (int n = 0; n < 4; ++n) bv[n] = bp[nbase + wc * 64 + n * 16 + ln];
#pragma unroll
  for (int m = 0; m < 4; ++m)
#pragma unroll
    for (int n = 0; n < 4; ++n)
#pragma unroll
      for (int r = 0; r < 4; ++r) {
        float v = (acc[m][n][r] + bv[n]) * scale;
        if (RELU) v = fmaxf(v, 0.f);
        const size_t idx = (size_t)(m0 + wr * 64 + m * 16 + g * 4 + r) * N
                         + n0 + wc * 64 + n * 16 + ln;
        if (OUT16) ((f16*)Cv)[idx] = (f16)v;
        else       ((float*)Cv)[idx] = v;
      }
}

// ---------------------------------------------------------------------------
// Flash attention, swapped-QK^T structure (fp16 MFMA 32x32x16, fp32 softmax).
// Round-5 changes: single-barrier double-buffered pipeline (K gload + V reg
// prefetch issued BEFORE compute, V^T scatter AFTER compute); XOR-swizzled
// V^T layout (conflict-free scatter writes); defer-max (THR=8, exp2 domain);
// tree max/sum reductions; s_setprio around MFMA clusters.
template<int BASE>
__device__ __forceinline__ f16x8 pack_frag(f32x16 p) {
  f16x8 r;
#pragma unroll
  for (int j = 0; j < 8; ++j) r[j] = (f16)p[BASE + j];
  return r;
}

#define VSTRIDE 68   // f16 row stride of V^T (d-major)
#define NKT (SEQ / 64)

__global__ __launch_bounds__(256, 2)
void attention(const f16* __restrict__ qkv, f16* __restrict__ ctx) {
  __shared__ f16 Ks[2][64 * 64];          // unit u=key*8+c : K[key][8*(c^(key&7))]
  __shared__ f16 VTs[2][64 * VSTRIDE];    // VT[d][key ^ (((d>>3)&7)<<2)]
  const int tid = threadIdx.x;
  const int l = tid & 63, w = tid >> 6;
  const int ln = l & 31, hi = l >> 5;
  const int bh = blockIdx.y, b = bh >> 4, h = bh & 15;
  const int q0 = blockIdx.x * 128;

  // Q B-fragments (held whole kernel); q pre-scaled by 0.125*log2e
  f16x8 qf[4];
  {
    const f16* qp = qkv + (size_t)(b * SEQ + q0 + w * 32 + ln) * 3072 + h * 64 + hi * 8;
#pragma unroll
    for (int kc = 0; kc < 4; ++kc) qf[kc] = *(const f16x8*)(qp + kc * 16);
  }

  f32x16 o0 = {}, o1 = {};
  float mrow = -1e30f, lrow = 0.f;

  const int skey = tid >> 3, sc = tid & 7;   // V/K staging coords
  const f16* kbase = qkv + (size_t)(b * SEQ) * 3072 + 1024 + h * 64;
  const f16* vbase = qkv + (size_t)(b * SEQ) * 3072 + 2048 + h * 64;
  // V^T scatter base: d = sc*8+j, key = skey (+32): swz = sc for all j<8
  const int wbase = sc * 8 * VSTRIDE + (skey ^ (sc << 2));

  auto gloadK = [&](int buf, int kt) {
#pragma unroll
    for (int p = 0; p < 2; ++p) {
      const int key = p * 32 + skey;
      gload16(kbase + (size_t)(kt * 64 + key) * 3072 + 8 * (sc ^ (key & 7)),
              (void*)&Ks[buf][(p * 256 + w * 64) * 8]);
    }
  };
  auto scatterV = [&](int buf, f16x8 va, f16x8 vb2) {
#pragma unroll
    for (int j = 0; j < 8; ++j) {
      VTs[buf][wbase + VSTRIDE * j] = va[j];
      VTs[buf][wbase + VSTRIDE * j + 32] = vb2[j];
    }
  };

  { // prologue: stage tile 0
    const f16* vp = vbase + (size_t)skey * 3072 + sc * 8;
    f16x8 va = *(const f16x8*)vp;
    f16x8 vb2 = *(const f16x8*)(vp + (size_t)32 * 3072);
    gloadK(0, 0);
    scatterV(0, va, vb2);
  }
  __syncthreads();

  const int sw0 = (ln >> 3) << 2;
  const int db0 = ln * VSTRIDE, db1 = (32 + ln) * VSTRIDE;

  auto body = [&](int kt, int cur) {
    const int nxt = cur ^ 1;
    f16x8 vna = {}, vnb = {};
    const bool more = (kt + 1 < NKT);
    if (more) {   // issue next tile's loads BEFORE compute (latency hides)
      const f16* vp = vbase + (size_t)((kt + 1) * 64 + skey) * 3072 + sc * 8;
      vna = *(const f16x8*)vp;
      vnb = *(const f16x8*)(vp + (size_t)32 * 3072);
      gloadK(nxt, kt + 1);
    }
    // ---- S^T = K @ Q^T
    f32x16 st0 = {}, st1 = {};
    __builtin_amdgcn_s_setprio(1);
#pragma unroll
    for (int kc = 0; kc < 4; ++kc) {
      const int m = kc * 2 + hi;
      const f16x8 kf0 = *(const f16x8*)&Ks[cur][(ln * 8 + (m ^ (ln & 7))) * 8];
      const f16x8 kf1 = *(const f16x8*)&Ks[cur][((32 + ln) * 8 + (m ^ (ln & 7))) * 8];
      st0 = __builtin_amdgcn_mfma_f32_32x32x16_f16(kf0, qf[kc], st0, 0, 0, 0);
      st1 = __builtin_amdgcn_mfma_f32_32x32x16_f16(kf1, qf[kc], st1, 0, 0, 0);
    }
    __builtin_amdgcn_s_setprio(0);

    // ---- online softmax (lane-local rows), tree reduce + defer-max
    float tm[16];
#pragma unroll
    for (int r = 0; r < 16; ++r) tm[r] = fmaxf(st0[r], st1[r]);
#pragma unroll
    for (int s2 = 8; s2 >= 1; s2 >>= 1)
#pragma unroll
      for (int r = 0; r < s2; ++r) tm[r] = fmaxf(tm[r], tm[r + s2]);
    const float mt = fmaxf(tm[0], __shfl_xor(tm[0], 32));
    if (!__all(mt <= mrow + 8.f)) {
      const float mn = fmaxf(mrow, mt);
      const float al = exp2f(mrow - mn);
      mrow = mn;
      lrow *= al;
#pragma unroll
      for (int r = 0; r < 16; ++r) { o0[r] *= al; o1[r] *= al; }
    }
    float ts[16];
#pragma unroll
    for (int r = 0; r < 16; ++r) {
      st0[r] = exp2f(st0[r] - mrow);
      st1[r] = exp2f(st1[r] - mrow);
      ts[r] = st0[r] + st1[r];
    }
#pragma unroll
    for (int s2 = 8; s2 >= 1; s2 >>= 1)
#pragma unroll
      for (int r = 0; r < s2; ++r) ts[r] += ts[r + s2];
    lrow += ts[0] + __shfl_xor(ts[0], 32);

    // ---- P fragments (in-lane pack; PV key order == S^T register order)
    f16x8 pf[4];
    pf[0] = pack_frag<0>(st0); pf[1] = pack_frag<8>(st0);
    pf[2] = pack_frag<0>(st1); pf[3] = pack_frag<8>(st1);

    // ---- O^T += V^T @ P^T
    __builtin_amdgcn_s_setprio(1);
#pragma unroll
    for (int s = 0; s < 4; ++s) {
      const int k0 = 16 * s + 4 * hi;
      {
        const int p0 = k0 ^ sw0;
        f16x4 x = *(const f16x4*)&VTs[cur][db0 + p0];
        f16x4 y = *(const f16x4*)&VTs[cur][db0 + (p0 ^ 8)];
        f16x8 vf = __builtin_shufflevector(x, y, 0, 1, 2, 3, 4, 5, 6, 7);
        o0 = __builtin_amdgcn_mfma_f32_32x32x16_f16(vf, pf[s], o0, 0, 0, 0);
      }
      {
        const int p1 = k0 ^ sw0 ^ 16;
        f16x4 x = *(const f16x4*)&VTs[cur][db1 + p1];
        f16x4 y = *(const f16x4*)&VTs[cur][db1 + (p1 ^ 8)];
        f16x8 vf = __builtin_shufflevector(x, y, 0, 1, 2, 3, 4, 5, 6, 7);
        o1 = __builtin_amdgcn_mfma_f32_32x32x16_f16(vf, pf[s], o1, 0, 0, 0);
      }
    }
    __builtin_amdgcn_s_setprio(0);

    if (more) scatterV(nxt, vna, vnb);   // V regs arrived during compute
    __syncthreads();                     // drains gloadK(nxt) + scatter lgkm
  };

#pragma unroll 1
  for (int kt = 0; kt < NKT; kt += 2) { body(kt, 0); body(kt + 1, 1); }

  // ---- write ctx (f16): O^T lane l holds d=(r&3)+8*(r>>2)+4*hi (+32 for o1)
  const float inv = 1.f / lrow;
  f16* cp = ctx + (size_t)(b * SEQ + q0 + w * 32 + ln) * EMBED + h * 64;
#pragma unroll
  for (int r = 0; r < 16; ++r) {
    const int drow = (r & 3) + 8 * (r >> 2) + 4 * hi;
    cp[drow] = (f16)(o0[r] * inv);
    cp[32 + drow] = (f16)(o1[r] * inv);
  }
}

// ---------------------------------------------------------------------------
// out = LayerNorm(resid + bias + sum_p parts[p]) * g + be  (unchanged)
template<int NP, int OUT16>
__global__ __launch_bounds__(256, 4)
void add_ln(const float* parts, const float* __restrict__ bias,
            const float* resid, const float* __restrict__ gam,
            const float* __restrict__ bet, float* out, f16* __restrict__ out16) {
  const int t = blockIdx.x;
  const int tid = threadIdx.x;
  const size_t base = (size_t)t * EMBED + tid * 4;
  float4 rv = *(const float4*)(resid + base);
  float4 bb = *(const float4*)(bias + tid * 4);
  float x0 = rv.x + bb.x, x1 = rv.y + bb.y, x2 = rv.z + bb.z, x3 = rv.w + bb.w;
#pragma unroll
  for (int p = 0; p < NP; ++p) {
    float4 pv = *(const float4*)(parts + (size_t)p * TOK * EMBED + base);
    x0 += pv.x; x1 += pv.y; x2 += pv.z; x3 += pv.w;
  }
  float s1 = x0 + x1 + x2 + x3;
  float s2 = x0 * x0 + x1 * x1 + x2 * x2 + x3 * x3;
  for (int off = 1; off < 64; off <<= 1) {
    s1 += __shfl_xor(s1, off);
    s2 += __shfl_xor(s2, off);
  }
  __shared__ float red[8];
  if ((tid & 63) == 0) { red[(tid >> 6) * 2] = s1; red[(tid >> 6) * 2 + 1] = s2; }
  __syncthreads();
  s1 = red[0] + red[2] + red[4] + red[6];
  s2 = red[1] + red[3] + red[5] + red[7];
  const float mu = s1 * (1.f / EMBED);
  const float var = s2 * (1.f / EMBED) - mu * mu;
  const float rstd = rsqrtf(var + 1e-6f);
  float4 gv = *(const float4*)(gam + tid * 4);
  float4 bv = *(const float4*)(bet + tid * 4);
  float4 ov;
  ov.x = (x0 - mu) * rstd * gv.x + bv.x;
  ov.y = (x1 - mu) * rstd * gv.y + bv.y;
  ov.z = (x2 - mu) * rstd * gv.z + bv.z;
  ov.w = (x3 - mu) * rstd * gv.w + bv.w;
  *(float4*)(out + base) = ov;
  if (OUT16) {
    f16x4 hh;
    hh[0] = (f16)ov.x; hh[1] = (f16)ov.y; hh[2] = (f16)ov.z; hh[3] = (f16)ov.w;
    *(f16x4*)(out16 + base) = hh;
  }
}

// ---------------------------------------------------------------------------
// Wt[N][K] f16 = transpose(in[K][N] f32); 32x32 tiles  (unchanged)
__device__ __forceinline__ void transpose_tile(const float* in, f16* out,
                                               int K, int N, int k0, int n0, int tid) {
  __shared__ float t[32][33];
  {
    const int ky = tid >> 3, nx = (tid & 7) * 4;
    float4 f = *(const float4*)(in + (size_t)(k0 + ky) * N + n0 + nx);
    t[ky][nx] = f.x; t[ky][nx + 1] = f.y; t[ky][nx + 2] = f.z; t[ky][nx + 3] = f.w;
  }
  __syncthreads();
  const int ny = tid >> 3, kx = (tid & 7) * 4;
  f16x4 hh;
  hh[0] = (f16)t[kx][ny];     hh[1] = (f16)t[kx + 1][ny];
  hh[2] = (f16)t[kx + 2][ny]; hh[3] = (f16)t[kx + 3][ny];
  *(f16x4*)(out + (size_t)(n0 + ny) * K + k0 + kx) = hh;
}

__global__ __launch_bounds__(256, 4)
void transpose_w(const float* __restrict__ in, f16* __restrict__ out,
                 int K, int N) {
  transpose_tile(in, out, K, N, blockIdx.y * 32, blockIdx.x * 32, threadIdx.x);
}

__global__ __launch_bounds__(256, 4)
void transpose_qkv(const float* __restrict__ w0, const float* __restrict__ w1,
                   const float* __restrict__ w2, f16* __restrict__ out) {
  const float* in = (blockIdx.z == 0) ? w0 : (blockIdx.z == 1) ? w1 : w2;
  f16* o = out + (size_t)blockIdx.z * 1024 * 1024;
  transpose_tile(in, o, 1024, 1024, blockIdx.y * 32, blockIdx.x * 32, threadIdx.x);
}

// ---------------------------------------------------------------------------
extern "C" void kernel_launch(void* const* d_in, const int* in_sizes, int n_in,
                              void* d_out, int out_size, void* d_ws, size_t ws_size,
                              hipStream_t stream) {
  const float* x    = (const float*)d_in[0];
  const float* Wq   = (const float*)d_in[1];
  const float* bq   = (const float*)d_in[2];
  const float* Wk   = (const float*)d_in[3];
  const float* bk   = (const float*)d_in[4];
  const float* Wv   = (const float*)d_in[5];
  const float* bv   = (const float*)d_in[6];
  const float* Wo   = (const float*)d_in[7];
  const float* bo   = (const float*)d_in[8];
  const float* ln1g = (const float*)d_in[9];
  const float* ln1b = (const float*)d_in[10];
  const float* W1   = (const float*)d_in[11];
  const float* b1   = (const float*)d_in[12];
  const float* W2   = (const float*)d_in[13];
  const float* b2   = (const float*)d_in[14];
  const float* ln2g = (const float*)d_in[15];
  const float* ln2b = (const float*)d_in[16];
  float* out = (float*)d_out;

  // workspace (96 MB):
  //  0: WtQKV f16 6MB | 6: WtO 2MB | 8: Wt1 8MB | 16: Wt2 8MB
  // 24: qkv f16 24MB (later hid f16 32MB over 24-56) | 48: ctx f16 8MB
  // 56: parts f32 2x16MB | 88: x1h f16 8MB.  x1 (f32) lives in d_out.
  char* ws = (char*)d_ws;
  const size_t MB = 1024 * 1024;
  f16*   WtQKV = (f16*)(ws);
  f16*   WtO   = (f16*)(ws + 6 * MB);
  f16*   Wt1   = (f16*)(ws + 8 * MB);
  f16*   Wt2   = (f16*)(ws + 16 * MB);
  f16*   qkv   = (f16*)(ws + 24 * MB);
  f16*   ctx   = (f16*)(ws + 48 * MB);
  float* parts = (float*)(ws + 56 * MB);
  f16*   x1h   = (f16*)(ws + 88 * MB);
  f16*   hid   = (f16*)(ws + 24 * MB);
  float* x1    = out;   // d_out doubles as x1 storage

  const dim3 blk(256);
  transpose_qkv<<<dim3(32, 32, 3), blk, 0, stream>>>(Wq, Wk, Wv, WtQKV);
  transpose_w<<<dim3(32, 32), blk, 0, stream>>>(Wo, WtO, 1024, 1024);
  transpose_w<<<dim3(128, 32), blk, 0, stream>>>(W1, Wt1, 1024, 4096);
  transpose_w<<<dim3(32, 128), blk, 0, stream>>>(W2, Wt2, 4096, 1024);

  gemm_f16<0, 0, 1, 1, 1><<<768, blk, 0, stream>>>(x, WtQKV, bq, bk, bv, qkv, 3072, 1024, 24);
  attention<<<dim3(16, 32), blk, 0, stream>>>(qkv, ctx);
  gemm_f16<1, 0, 0, 0, 2><<<512, blk, 0, stream>>>(ctx, WtO, nullptr, nullptr, nullptr, parts, 1024, 1024, 8);
  add_ln<2, 1><<<4096, blk, 0, stream>>>(parts, bo, x, ln1g, ln1b, x1, x1h);
  gemm_f16<1, 1, 1, 0, 1><<<1024, blk, 0, stream>>>(x1h, Wt1, b1, nullptr, nullptr, hid, 4096, 1024, 32);
  gemm_f16<1, 0, 0, 0, 2><<<512, blk, 0, stream>>>(hid, Wt2, nullptr, nullptr, nullptr, parts, 1024, 4096, 8);
  add_ln<2, 0><<<4096, blk, 0, stream>>>(parts, b2, x1, ln2g, ln2b, out, nullptr);
}